// Round 1
// baseline (7249.567 us; speedup 1.0000x reference)
//
#include <hip/hip_runtime.h>

// MSDeformAttn Transformer encoder (Deformable-DETR), MI355X fp32 baseline.
// B=2 D=256 NH=8 DH=32 LV=4 NP=4 NL=6 DFF=1024, S=16660.

constexpr int kB  = 2;
constexpr int kD  = 256;
constexpr int kNH = 8;
constexpr int kDH = 32;
constexpr int kLV = 4;
constexpr int kNP = 4;
constexpr int kNL = 6;
constexpr int kDFF = 1024;
constexpr int kS  = 16660;                 // 112^2 + 56^2 + 28^2 + 14^2
constexpr int kM  = kB * kS;               // 33320 rows

// ---------------------------------------------------------------------------
// Input flatten+transpose: src/pos [B,D,H,W] -> x/pos [B,S,D]; pos += lvl_emb
// ---------------------------------------------------------------------------
__global__ __launch_bounds__(256) void build_xpos_k(
    const float* __restrict__ src, const float* __restrict__ pos,
    const float* __restrict__ lemb, float* __restrict__ xout,
    float* __restrict__ posout, int HW, int s0, int lvl)
{
  __shared__ float ts[32][33];
  __shared__ float tp[32][33];
  const int b  = blockIdx.z;
  const int p0 = blockIdx.x * 32, d0 = blockIdx.y * 32;
  const int tx = threadIdx.x, ty = threadIdx.y;   // (32, 8)
  for (int dd = ty; dd < 32; dd += 8) {
    int p = p0 + tx;
    if (p < HW) {
      size_t idx = ((size_t)b * kD + (d0 + dd)) * (size_t)HW + p;
      ts[dd][tx] = src[idx];
      tp[dd][tx] = pos[idx];
    }
  }
  __syncthreads();
  for (int pp = ty; pp < 32; pp += 8) {
    int p = p0 + pp, d = d0 + tx;
    if (p < HW) {
      size_t o = ((size_t)b * kS + (s0 + p)) * (size_t)kD + d;
      xout[o]   = ts[tx][pp];
      posout[o] = tp[tx][pp] + lemb[lvl * kD + d];
    }
  }
}

// ---------------------------------------------------------------------------
// Tiled fp32 GEMM: C[M,N] = A[M,K] @ W[K,N] + bias (+A2 on A-read, +Rsd, relu)
// BM=BN=64, BK=16, 256 threads, 4x4 acc per thread.
// ---------------------------------------------------------------------------
template<int ADDPOS, int RELU, int RES>
__global__ __launch_bounds__(256) void sgemm_k(
    const float* __restrict__ A, const float* __restrict__ A2,
    const float* __restrict__ W, const float* __restrict__ bias,
    const float* __restrict__ Rsd, float* __restrict__ C,
    int M, int N, int K)
{
  __shared__ float As[16][65];   // [k][m], padded
  __shared__ float Ws[16][64];   // [k][n]
  const int tid = threadIdx.x;
  const int bm = blockIdx.y * 64, bn = blockIdx.x * 64;
  const int tm = tid >> 4, tn = tid & 15;
  const int la_r = tid >> 2, la_c = (tid & 3) << 2;   // A: 64 rows x 4 float4
  const int lw_r = tid >> 4, lw_c = (tid & 15) << 2;  // W: 16 rows x 16 float4

  float acc[4][4] = {};
  const int  ar  = bm + la_r;
  const bool arv = (ar < M);
  const float* Arow  = A  + (size_t)(arv ? ar : 0) * K + la_c;
  const float* A2row = ADDPOS ? (A2 + (size_t)(arv ? ar : 0) * K + la_c) : nullptr;

  for (int k0 = 0; k0 < K; k0 += 16) {
    float4 av = make_float4(0.f, 0.f, 0.f, 0.f);
    if (arv) {
      av = *(const float4*)(Arow + k0);
      if (ADDPOS) {
        float4 pv = *(const float4*)(A2row + k0);
        av.x += pv.x; av.y += pv.y; av.z += pv.z; av.w += pv.w;
      }
    }
    As[la_c + 0][la_r] = av.x;
    As[la_c + 1][la_r] = av.y;
    As[la_c + 2][la_r] = av.z;
    As[la_c + 3][la_r] = av.w;
    *(float4*)&Ws[lw_r][lw_c] = *(const float4*)&W[(size_t)(k0 + lw_r) * N + bn + lw_c];
    __syncthreads();
#pragma unroll
    for (int k = 0; k < 16; ++k) {
      float a[4], w[4];
#pragma unroll
      for (int i = 0; i < 4; ++i) a[i] = As[k][tm * 4 + i];
#pragma unroll
      for (int j = 0; j < 4; ++j) w[j] = Ws[k][tn * 4 + j];
#pragma unroll
      for (int i = 0; i < 4; ++i)
#pragma unroll
        for (int j = 0; j < 4; ++j)
          acc[i][j] = fmaf(a[i], w[j], acc[i][j]);
    }
    __syncthreads();
  }

#pragma unroll
  for (int i = 0; i < 4; ++i) {
    int r = bm + tm * 4 + i;
    if (r < M) {
#pragma unroll
      for (int j = 0; j < 4; ++j) {
        int c = bn + tn * 4 + j;
        float v = acc[i][j] + bias[c];
        if (RES) v += Rsd[(size_t)r * N + c];
        if (RELU) v = fmaxf(v, 0.f);
        C[(size_t)r * N + c] = v;
      }
    }
  }
}

// ---------------------------------------------------------------------------
// Softmax over groups of 16 (LV*NP) — one thread per (b,s,h)
// ---------------------------------------------------------------------------
__global__ __launch_bounds__(256) void softmax16_k(float* __restrict__ aw, int n)
{
  int t = blockIdx.x * 256 + threadIdx.x;
  if (t >= n) return;
  float4* p = (float4*)(aw + (size_t)t * 16);
  float4 q0 = p[0], q1 = p[1], q2 = p[2], q3 = p[3];
  float v[16] = {q0.x, q0.y, q0.z, q0.w, q1.x, q1.y, q1.z, q1.w,
                 q2.x, q2.y, q2.z, q2.w, q3.x, q3.y, q3.z, q3.w};
  float m = v[0];
#pragma unroll
  for (int i = 1; i < 16; ++i) m = fmaxf(m, v[i]);
  float s = 0.f;
#pragma unroll
  for (int i = 0; i < 16; ++i) { v[i] = expf(v[i] - m); s += v[i]; }
  float inv = 1.0f / s;
#pragma unroll
  for (int i = 0; i < 16; ++i) v[i] *= inv;
  p[0] = make_float4(v[0],  v[1],  v[2],  v[3]);
  p[1] = make_float4(v[4],  v[5],  v[6],  v[7]);
  p[2] = make_float4(v[8],  v[9],  v[10], v[11]);
  p[3] = make_float4(v[12], v[13], v[14], v[15]);
}

// ---------------------------------------------------------------------------
// MS deformable attention sampling.
// val [B,S,NH,DH], off [B,S,NH,LV,NP,2], aw [B,S,NH,LV,NP] -> out [B,S,D]
// block = 256 threads = (h, dh); grid = B*S
// ---------------------------------------------------------------------------
__global__ __launch_bounds__(256) void msdeform_k(
    const float* __restrict__ val, const float* __restrict__ off,
    const float* __restrict__ aw, float* __restrict__ out)
{
  const int bs = blockIdx.x;
  const int b = bs / kS, s = bs - b * kS;
  const int h = threadIdx.x >> 5, dh = threadIdx.x & 31;

  int ls, side;
  if (s < 12544)      { ls = s;         side = 112; }
  else if (s < 15680) { ls = s - 12544; side = 56;  }
  else if (s < 16464) { ls = s - 15680; side = 28;  }
  else                { ls = s - 16464; side = 14;  }
  const float rx = ((ls % side) + 0.5f) / (float)side;
  const float ry = ((ls / side) + 0.5f) / (float)side;

  const float* offp = off + ((size_t)bs * kNH + h) * (kLV * kNP * 2);
  const float* awp  = aw  + ((size_t)bs * kNH + h) * (kLV * kNP);

  const int sides[4]  = {112, 56, 28, 14};
  const int starts[4] = {0, 12544, 15680, 16464};

  float acc = 0.f;
#pragma unroll
  for (int l = 0; l < 4; ++l) {
    const int   Wl   = sides[l];
    const float invW = 1.0f / (float)Wl;
    const float* vbase = val + ((size_t)b * kS + starts[l]) * kD + h * kDH + dh;
#pragma unroll
    for (int p = 0; p < 4; ++p) {
      const float ox = offp[(l * kNP + p) * 2 + 0];
      const float oy = offp[(l * kNP + p) * 2 + 1];
      const float a  = awp[l * kNP + p];
      const float xx = (rx + ox * invW) * (float)Wl - 0.5f;
      const float yy = (ry + oy * invW) * (float)Wl - 0.5f;
      const float xf = floorf(xx), yf = floorf(yy);
      const float lx = xx - xf, ly = yy - yf;
      const int x0 = (int)xf, y0 = (int)yf;
      const int x1 = x0 + 1,  y1 = y0 + 1;
      const float w00 = (1.f - lx) * (1.f - ly), w10 = lx * (1.f - ly);
      const float w01 = (1.f - lx) * ly,         w11 = lx * ly;
      const bool xv0 = (unsigned)x0 < (unsigned)Wl, xv1 = (unsigned)x1 < (unsigned)Wl;
      const bool yv0 = (unsigned)y0 < (unsigned)Wl, yv1 = (unsigned)y1 < (unsigned)Wl;
      float v00 = (xv0 && yv0) ? vbase[(size_t)(y0 * Wl + x0) * kD] : 0.f;
      float v10 = (xv1 && yv0) ? vbase[(size_t)(y0 * Wl + x1) * kD] : 0.f;
      float v01 = (xv0 && yv1) ? vbase[(size_t)(y1 * Wl + x0) * kD] : 0.f;
      float v11 = (xv1 && yv1) ? vbase[(size_t)(y1 * Wl + x1) * kD] : 0.f;
      acc += a * (v00 * w00 + v10 * w10 + v01 * w01 + v11 * w11);
    }
  }
  out[(size_t)bs * kD + h * kDH + dh] = acc;
}

// ---------------------------------------------------------------------------
// In-place LayerNorm over D=256; one block per row, two-pass (mean then var)
// ---------------------------------------------------------------------------
__global__ __launch_bounds__(256) void layernorm_k(
    float* __restrict__ x, const float* __restrict__ g, const float* __restrict__ bta)
{
  const int row = blockIdx.x;
  const int t = threadIdx.x;
  float* p = x + (size_t)row * kD;
  float v = p[t];
  __shared__ float red[4];
  float s = v;
#pragma unroll
  for (int m = 1; m <= 32; m <<= 1) s += __shfl_xor(s, m, 64);
  if ((t & 63) == 0) red[t >> 6] = s;
  __syncthreads();
  const float mean = (red[0] + red[1] + red[2] + red[3]) * (1.0f / kD);
  __syncthreads();
  const float dv = v - mean;
  float s2 = dv * dv;
#pragma unroll
  for (int m = 1; m <= 32; m <<= 1) s2 += __shfl_xor(s2, m, 64);
  if ((t & 63) == 0) red[t >> 6] = s2;
  __syncthreads();
  const float var = (red[0] + red[1] + red[2] + red[3]) * (1.0f / kD);
  const float inv = 1.0f / sqrtf(var + 1e-5f);
  p[t] = dv * inv * g[t] + bta[t];
}

// ---------------------------------------------------------------------------
// Final: copy x -> d_out, append spatial_shapes + level_start_index (as f32)
// ---------------------------------------------------------------------------
__global__ __launch_bounds__(256) void finalize_k(
    const float* __restrict__ x, float* __restrict__ out)
{
  const size_t n = (size_t)kM * kD;
  for (size_t i = (size_t)blockIdx.x * blockDim.x + threadIdx.x; i < n;
       i += (size_t)gridDim.x * blockDim.x)
    out[i] = x[i];
  if (blockIdx.x == 0 && threadIdx.x == 0) {
    out[n + 0] = 112.f; out[n + 1] = 112.f;
    out[n + 2] = 56.f;  out[n + 3] = 56.f;
    out[n + 4] = 28.f;  out[n + 5] = 28.f;
    out[n + 6] = 14.f;  out[n + 7] = 14.f;
    out[n + 8] = 0.f;   out[n + 9] = 12544.f;
    out[n + 10] = 15680.f; out[n + 11] = 16464.f;
  }
}

// ---------------------------------------------------------------------------
extern "C" void kernel_launch(void* const* d_in, const int* in_sizes, int n_in,
                              void* d_out, int out_size, void* d_ws, size_t ws_size,
                              hipStream_t stream)
{
  const float* src[4] = {(const float*)d_in[0], (const float*)d_in[2],
                         (const float*)d_in[4], (const float*)d_in[6]};
  const float* pos[4] = {(const float*)d_in[1], (const float*)d_in[3],
                         (const float*)d_in[5], (const float*)d_in[7]};
  const float* lemb  = (const float*)d_in[8];
  const float* off_w = (const float*)d_in[9];
  const float* off_b = (const float*)d_in[10];
  const float* aw_w  = (const float*)d_in[11];
  const float* aw_b  = (const float*)d_in[12];
  const float* val_w = (const float*)d_in[13];
  const float* val_b = (const float*)d_in[14];
  const float* out_w = (const float*)d_in[15];
  const float* out_b = (const float*)d_in[16];
  const float* ln1_s = (const float*)d_in[17];
  const float* ln1_b = (const float*)d_in[18];
  const float* ff1_w = (const float*)d_in[19];
  const float* ff1_b = (const float*)d_in[20];
  const float* ff2_w = (const float*)d_in[21];
  const float* ff2_b = (const float*)d_in[22];
  const float* ln2_s = (const float*)d_in[23];
  const float* ln2_b = (const float*)d_in[24];

  const size_t SZX = (size_t)kM * kD;   // 8,529,920 floats
  float* ws   = (float*)d_ws;
  float* posb = (float*)d_out;          // pos lives in d_out until finalize
  float* xb   = ws;                      // [SZX]
  float* Rr   = ws + SZX;                // reusable region [4*SZX]
  float* offb = Rr;                      // [SZX]
  float* awb  = Rr + SZX;                // [SZX/2]
  float* valb = Rr + SZX + SZX / 2;      // [SZX]
  float* attb = Rr + 2 * SZX + SZX / 2;  // [SZX]
  float* ffb  = Rr;                      // [4*SZX] (ff phase; aliases the above)

  const int sides[4]  = {112, 56, 28, 14};
  const int starts[4] = {0, 12544, 15680, 16464};

  // Build x0 and pos (+level_embed)
  for (int l = 0; l < 4; ++l) {
    int HW = sides[l] * sides[l];
    dim3 g((HW + 31) / 32, kD / 32, kB);
    build_xpos_k<<<g, dim3(32, 8), 0, stream>>>(src[l], pos[l], lemb, xb, posb,
                                                HW, starts[l], l);
  }

  const dim3 blk(256);
  const int gy = (kM + 63) / 64;   // 521

  for (int i = 0; i < kNL; ++i) {
    // off = (x+pos) @ off_w + off_b
    sgemm_k<1, 0, 0><<<dim3(256 / 64, gy), blk, 0, stream>>>(
        xb, posb, off_w + (size_t)i * kD * 256, off_b + i * 256, nullptr, offb,
        kM, 256, kD);
    // aw_raw = (x+pos) @ aw_w + aw_b
    sgemm_k<1, 0, 0><<<dim3(128 / 64, gy), blk, 0, stream>>>(
        xb, posb, aw_w + (size_t)i * kD * 128, aw_b + i * 128, nullptr, awb,
        kM, 128, kD);
    softmax16_k<<<(kM * kNH + 255) / 256, blk, 0, stream>>>(awb, kM * kNH);
    // val = x @ val_w + val_b
    sgemm_k<0, 0, 0><<<dim3(256 / 64, gy), blk, 0, stream>>>(
        xb, nullptr, val_w + (size_t)i * kD * kD, val_b + i * kD, nullptr, valb,
        kM, kD, kD);
    // sampling
    msdeform_k<<<kM, blk, 0, stream>>>(valb, offb, awb, attb);
    // x = x + attn @ out_w + out_b  (in place), then LN1
    sgemm_k<0, 0, 1><<<dim3(256 / 64, gy), blk, 0, stream>>>(
        attb, nullptr, out_w + (size_t)i * kD * kD, out_b + i * kD, xb, xb,
        kM, kD, kD);
    layernorm_k<<<kM, blk, 0, stream>>>(xb, ln1_s + i * kD, ln1_b + i * kD);
    // ffmid = relu(x @ ff1_w + ff1_b)
    sgemm_k<0, 1, 0><<<dim3(kDFF / 64, gy), blk, 0, stream>>>(
        xb, nullptr, ff1_w + (size_t)i * kD * kDFF, ff1_b + i * kDFF, nullptr,
        ffb, kM, kDFF, kD);
    // x = x + ffmid @ ff2_w + ff2_b (in place), then LN2
    sgemm_k<0, 0, 1><<<dim3(kD / 64, gy), blk, 0, stream>>>(
        ffb, nullptr, ff2_w + (size_t)i * kDFF * kD, ff2_b + i * kD, xb, xb,
        kM, kD, kDFF);
    layernorm_k<<<kM, blk, 0, stream>>>(xb, ln2_s + i * kD, ln2_b + i * kD);
  }

  finalize_k<<<2048, blk, 0, stream>>>(xb, (float*)d_out);
}

// Round 2
// 3037.691 us; speedup vs baseline: 2.3865x; 2.3865x over previous
//
#include <hip/hip_runtime.h>

// MSDeformAttn Transformer encoder (Deformable-DETR), MI355X.
// Round 2: bf16 MFMA GEMMs (m97 structure) + restructured sampling kernel.

constexpr int kB  = 2;
constexpr int kD  = 256;
constexpr int kNH = 8;
constexpr int kLV = 4;
constexpr int kNP = 4;
constexpr int kNL = 6;
constexpr int kDFF = 1024;
constexpr int kS  = 16660;                 // 112^2+56^2+28^2+14^2
constexpr int kM  = kB * kS;               // 33320
constexpr int kMp = 33408;                 // 261*128 (padded rows)
constexpr int kMT = kMp / 128;             // 261 row-tiles

typedef short bf16x8 __attribute__((ext_vector_type(8)));
typedef float f32x4  __attribute__((ext_vector_type(4)));

__device__ __forceinline__ unsigned short f2bf(float x) {
  union { float f; unsigned int u; } v; v.f = x;
  unsigned int r = v.u + 0x7FFFu + ((v.u >> 16) & 1u);
  return (unsigned short)(r >> 16);
}
__device__ __forceinline__ float bf2f(unsigned short u) {
  union { unsigned int u; float f; } v; v.u = ((unsigned int)u) << 16;
  return v.f;
}

#define GLOAD_LDS16(gp, lp)                                                    \
  __builtin_amdgcn_global_load_lds(                                            \
      (const __attribute__((address_space(1))) void*)(gp),                     \
      (__attribute__((address_space(3))) void*)(lp), 16, 0, 0)

// ---------------------------------------------------------------------------
// Input flatten+transpose; also emits bf16 x and bf16 q=x+pos.
// ---------------------------------------------------------------------------
__global__ __launch_bounds__(256) void build_xpos_k(
    const float* __restrict__ src, const float* __restrict__ pos,
    const float* __restrict__ lemb, float* __restrict__ xout,
    float* __restrict__ posout, unsigned short* __restrict__ xbf,
    unsigned short* __restrict__ qbf, int HW, int s0, int lvl)
{
  __shared__ float ts[32][33];
  __shared__ float tp[32][33];
  const int b  = blockIdx.z;
  const int p0 = blockIdx.x * 32, d0 = blockIdx.y * 32;
  const int tx = threadIdx.x, ty = threadIdx.y;   // (32, 8)
  for (int dd = ty; dd < 32; dd += 8) {
    int p = p0 + tx;
    if (p < HW) {
      size_t idx = ((size_t)b * kD + (d0 + dd)) * (size_t)HW + p;
      ts[dd][tx] = src[idx];
      tp[dd][tx] = pos[idx];
    }
  }
  __syncthreads();
  for (int pp = ty; pp < 32; pp += 8) {
    int p = p0 + pp, d = d0 + tx;
    if (p < HW) {
      size_t o = ((size_t)b * kS + (s0 + p)) * (size_t)kD + d;
      float x = ts[tx][pp];
      float pv = tp[tx][pp] + lemb[lvl * kD + d];
      xout[o] = x;
      posout[o] = pv;
      xbf[o] = f2bf(x);
      qbf[o] = f2bf(x + pv);
    }
  }
}

// ---------------------------------------------------------------------------
// Weight convert+transpose: W fp32 [NL][K][N] -> Wt bf16 [NL][rows][K] at rowoff
// ---------------------------------------------------------------------------
__global__ __launch_bounds__(256) void wconv_k(
    const float* __restrict__ W, unsigned short* __restrict__ Wt,
    int K, int N, int rowoff, int rowstotal)
{
  __shared__ float t[32][33];
  const int l = blockIdx.z;
  const int n0 = blockIdx.x * 32, k0 = blockIdx.y * 32;
  const int tx = threadIdx.x & 31, ty = threadIdx.x >> 5;
  const float* Wl = W + (size_t)l * K * N;
  unsigned short* Wtl = Wt + (size_t)l * rowstotal * K;
  for (int kk = ty; kk < 32; kk += 8)
    t[kk][tx] = Wl[(size_t)(k0 + kk) * N + n0 + tx];
  __syncthreads();
  for (int nn = ty; nn < 32; nn += 8)
    Wtl[(size_t)(rowoff + n0 + nn) * K + k0 + tx] = f2bf(t[tx][nn]);
}

__global__ __launch_bounds__(256) void biaspack_k(
    const float* __restrict__ ob, const float* __restrict__ ab,
    float* __restrict__ qb)
{
  int i = blockIdx.x * 256 + threadIdx.x;
  if (i >= kNL * 384) return;
  int l = i / 384, c = i - l * 384;
  qb[i] = (c < 256) ? ob[l * 256 + c] : ab[l * 128 + (c - 256)];
}

// ---------------------------------------------------------------------------
// bf16 MFMA GEMM: C[Mp,N] = A[Mp,K](bf16) @ Bt[N,K](bf16)^T + bias
// 128x128 tile, BK=32, 256 threads (4 waves, 2x2 of 64x64), m97 structure.
// ---------------------------------------------------------------------------
template<int RELU, int RES, int OUTBF>
__global__ __launch_bounds__(256) void hgemm_k(
    const unsigned short* __restrict__ A, const unsigned short* __restrict__ Bt,
    const float* __restrict__ bias, const float* __restrict__ Rsd,
    void* __restrict__ Cout, int N, int K)
{
  __shared__ unsigned short As[128 * 32];
  __shared__ unsigned short Bs[128 * 32];
  const int tid = threadIdx.x;
  const int bm = blockIdx.y * 128;
  const int bn = blockIdx.x * 128;
  const int lane = tid & 63;
  const int wave = tid >> 6;
  const int wr = (wave >> 1) * 64, wc = (wave & 1) * 64;
  const int l15 = lane & 15, l4 = lane >> 4;

  f32x4 acc[4][4] = {};

  const int c0 = tid, c1 = 256 + tid;
  const int r0 = c0 >> 2, kk0 = (c0 & 3) << 3;
  const int r1 = c1 >> 2, kk1 = (c1 & 3) << 3;
  const unsigned short* A0 = A + (size_t)(bm + r0) * K + kk0;
  const unsigned short* A1 = A + (size_t)(bm + r1) * K + kk1;
  const unsigned short* B0 = Bt + (size_t)(bn + r0) * K + kk0;
  const unsigned short* B1 = Bt + (size_t)(bn + r1) * K + kk1;

  for (int k0 = 0; k0 < K; k0 += 32) {
    GLOAD_LDS16(A0 + k0, (char*)As + c0 * 16);
    GLOAD_LDS16(A1 + k0, (char*)As + c1 * 16);
    GLOAD_LDS16(B0 + k0, (char*)Bs + c0 * 16);
    GLOAD_LDS16(B1 + k0, (char*)Bs + c1 * 16);
    __syncthreads();
    bf16x8 af[4], bfr[4];
#pragma unroll
    for (int m = 0; m < 4; ++m)
      af[m] = *(const bf16x8*)&As[(wr + m * 16 + l15) * 32 + l4 * 8];
#pragma unroll
    for (int n = 0; n < 4; ++n)
      bfr[n] = *(const bf16x8*)&Bs[(wc + n * 16 + l15) * 32 + l4 * 8];
#pragma unroll
    for (int m = 0; m < 4; ++m)
#pragma unroll
      for (int n = 0; n < 4; ++n)
        acc[m][n] = __builtin_amdgcn_mfma_f32_16x16x32_bf16(
            af[m], bfr[n], acc[m][n], 0, 0, 0);
    __syncthreads();
  }

#pragma unroll
  for (int n = 0; n < 4; ++n) {
    const int col = bn + wc + n * 16 + l15;
    const float bv = bias[col];
#pragma unroll
    for (int m = 0; m < 4; ++m) {
#pragma unroll
      for (int j = 0; j < 4; ++j) {
        const int row = bm + wr + m * 16 + l4 * 4 + j;
        float v = acc[m][n][j] + bv;
        if (RES) v += Rsd[(size_t)row * N + col];
        if (RELU) v = fmaxf(v, 0.f);
        if (OUTBF)
          ((unsigned short*)Cout)[(size_t)row * N + col] = f2bf(v);
        else
          ((float*)Cout)[(size_t)row * N + col] = v;
      }
    }
  }
}

// ---------------------------------------------------------------------------
// MS deformable attention sampling (+fused softmax).
// qout fp32 [Mp][384]: cols 0..255 = offsets, 256..383 = aw logits.
// val bf16 [Mp][256] -> out bf16 [Mp][256]. One block per query.
// ---------------------------------------------------------------------------
__global__ __launch_bounds__(256) void msdeform_k(
    const unsigned short* __restrict__ val, const float* __restrict__ qout,
    unsigned short* __restrict__ outbf)
{
  __shared__ int   sIdx[4 * 128];
  __shared__ float sW[4 * 128];
  const int bs = blockIdx.x;
  const int b = bs / kS, s = bs - b * kS;
  const int tid = threadIdx.x;

  if (tid < 128) {
    const int t = tid;
    const int lp = t & 15, l = lp >> 2;
    // softmax over the 16-lane group
    const float logit = qout[(size_t)bs * 384 + 256 + t];
    float mx = logit;
#pragma unroll
    for (int d2 = 1; d2 < 16; d2 <<= 1) mx = fmaxf(mx, __shfl_xor(mx, d2, 64));
    float e = __expf(logit - mx);
    float sm = e;
#pragma unroll
    for (int d2 = 1; d2 < 16; d2 <<= 1) sm += __shfl_xor(sm, d2, 64);
    const float a = e / sm;

    // reference point for this query
    int ls, sideq;
    if (s < 12544)      { ls = s;         sideq = 112; }
    else if (s < 15680) { ls = s - 12544; sideq = 56;  }
    else if (s < 16464) { ls = s - 15680; sideq = 28;  }
    else                { ls = s - 16464; sideq = 14;  }
    const float rx = ((ls % sideq) + 0.5f) / (float)sideq;
    const float ry = ((ls / sideq) + 0.5f) / (float)sideq;

    const int side  = 112 >> l;
    const int start = (l >= 1 ? 12544 : 0) + (l >= 2 ? 3136 : 0) + (l >= 3 ? 784 : 0);
    const float ox = qout[(size_t)bs * 384 + t * 2 + 0];
    const float oy = qout[(size_t)bs * 384 + t * 2 + 1];
    const float xx = rx * side + ox - 0.5f;
    const float yy = ry * side + oy - 0.5f;
    const float xf = floorf(xx), yf = floorf(yy);
    const float lx = xx - xf, ly = yy - yf;
    const int x0 = (int)xf, y0 = (int)yf;
    const float w00 = (1.f - lx) * (1.f - ly) * a, w10 = lx * (1.f - ly) * a;
    const float w01 = (1.f - lx) * ly * a,         w11 = lx * ly * a;
    const bool xv0 = (unsigned)x0 < (unsigned)side, xv1 = (unsigned)(x0 + 1) < (unsigned)side;
    const bool yv0 = (unsigned)y0 < (unsigned)side, yv1 = (unsigned)(y0 + 1) < (unsigned)side;
    const int cx0 = min(max(x0, 0), side - 1), cx1 = min(max(x0 + 1, 0), side - 1);
    const int cy0 = min(max(y0, 0), side - 1), cy1 = min(max(y0 + 1, 0), side - 1);
    const int rowbase = b * kS + start;
    sIdx[0 * 128 + t] = rowbase + cy0 * side + cx0;
    sIdx[1 * 128 + t] = rowbase + cy0 * side + cx1;
    sIdx[2 * 128 + t] = rowbase + cy1 * side + cx0;
    sIdx[3 * 128 + t] = rowbase + cy1 * side + cx1;
    sW[0 * 128 + t] = (xv0 && yv0) ? w00 : 0.f;
    sW[1 * 128 + t] = (xv1 && yv0) ? w10 : 0.f;
    sW[2 * 128 + t] = (xv0 && yv1) ? w01 : 0.f;
    sW[3 * 128 + t] = (xv1 && yv1) ? w11 : 0.f;
  }
  __syncthreads();

  const int h = tid >> 5, dh = tid & 31;
  const unsigned short* vb = val + h * 32 + dh;
  float acc = 0.f;
#pragma unroll
  for (int sp = 0; sp < 16; ++sp) {
    const int t = (h << 4) + sp;
#pragma unroll
    for (int c = 0; c < 4; ++c) {
      const int r = sIdx[c * 128 + t];
      const float w = sW[c * 128 + t];
      acc = fmaf(w, bf2f(vb[(size_t)r * 256]), acc);
    }
  }
  outbf[(size_t)bs * 256 + h * 32 + dh] = f2bf(acc);
}

// ---------------------------------------------------------------------------
// In-place LayerNorm over D=256 + bf16 x (and optional bf16 q=x+pos) emit.
// ---------------------------------------------------------------------------
template<int WQ>
__global__ __launch_bounds__(256) void layernorm_k(
    float* __restrict__ x, const float* __restrict__ g,
    const float* __restrict__ bta, const float* __restrict__ posb,
    unsigned short* __restrict__ xbf, unsigned short* __restrict__ qbf)
{
  const int row = blockIdx.x;
  const int t = threadIdx.x;
  float* p = x + (size_t)row * kD;
  float v = p[t];
  __shared__ float red[4];
  float sacc = v;
#pragma unroll
  for (int m = 1; m <= 32; m <<= 1) sacc += __shfl_xor(sacc, m, 64);
  if ((t & 63) == 0) red[t >> 6] = sacc;
  __syncthreads();
  const float mean = (red[0] + red[1] + red[2] + red[3]) * (1.0f / kD);
  __syncthreads();
  const float dv = v - mean;
  float s2 = dv * dv;
#pragma unroll
  for (int m = 1; m <= 32; m <<= 1) s2 += __shfl_xor(s2, m, 64);
  if ((t & 63) == 0) red[t >> 6] = s2;
  __syncthreads();
  const float var = (red[0] + red[1] + red[2] + red[3]) * (1.0f / kD);
  const float inv = 1.0f / sqrtf(var + 1e-5f);
  const float y = dv * inv * g[t] + bta[t];
  p[t] = y;
  xbf[(size_t)row * kD + t] = f2bf(y);
  if (WQ) qbf[(size_t)row * kD + t] = f2bf(y + posb[(size_t)row * kD + t]);
}

// ---------------------------------------------------------------------------
__global__ __launch_bounds__(256) void finalize_k(
    const float* __restrict__ x, float* __restrict__ out)
{
  const size_t n = (size_t)kM * kD;
  for (size_t i = (size_t)blockIdx.x * blockDim.x + threadIdx.x; i < n;
       i += (size_t)gridDim.x * blockDim.x)
    out[i] = x[i];
  if (blockIdx.x == 0 && threadIdx.x == 0) {
    out[n + 0] = 112.f; out[n + 1] = 112.f;
    out[n + 2] = 56.f;  out[n + 3] = 56.f;
    out[n + 4] = 28.f;  out[n + 5] = 28.f;
    out[n + 6] = 14.f;  out[n + 7] = 14.f;
    out[n + 8] = 0.f;   out[n + 9] = 12544.f;
    out[n + 10] = 15680.f; out[n + 11] = 16464.f;
  }
}

// ---------------------------------------------------------------------------
extern "C" void kernel_launch(void* const* d_in, const int* in_sizes, int n_in,
                              void* d_out, int out_size, void* d_ws, size_t ws_size,
                              hipStream_t stream)
{
  const float* src[4] = {(const float*)d_in[0], (const float*)d_in[2],
                         (const float*)d_in[4], (const float*)d_in[6]};
  const float* pos[4] = {(const float*)d_in[1], (const float*)d_in[3],
                         (const float*)d_in[5], (const float*)d_in[7]};
  const float* lemb  = (const float*)d_in[8];
  const float* off_w = (const float*)d_in[9];
  const float* off_b = (const float*)d_in[10];
  const float* aw_w  = (const float*)d_in[11];
  const float* aw_b  = (const float*)d_in[12];
  const float* val_w = (const float*)d_in[13];
  const float* val_b = (const float*)d_in[14];
  const float* out_w = (const float*)d_in[15];
  const float* out_b = (const float*)d_in[16];
  const float* ln1_s = (const float*)d_in[17];
  const float* ln1_b = (const float*)d_in[18];
  const float* ff1_w = (const float*)d_in[19];
  const float* ff1_b = (const float*)d_in[20];
  const float* ff2_w = (const float*)d_in[21];
  const float* ff2_b = (const float*)d_in[22];
  const float* ln2_s = (const float*)d_in[23];
  const float* ln2_b = (const float*)d_in[24];

  const size_t SZ = (size_t)kMp * kD;      // 8,552,448 floats
  float* ws   = (float*)d_ws;
  float* posb = (float*)d_out;             // pos lives in d_out until finalize
  float* xb   = ws;                        // fp32 [SZ]
  float* R    = ws + SZ;                   // reusable region [2.5*SZ floats]
  float* qout = R;                         // fp32 [Mp][384] = 1.5*SZ
  unsigned short* valbf = (unsigned short*)(R + SZ + SZ / 2);  // bf16 [Mp][256]
  unsigned short* attbf = (unsigned short*)(R + 2 * SZ);       // bf16 [Mp][256]
  unsigned short* ffbf  = (unsigned short*)R;                  // bf16 [Mp][1024]
  unsigned short* qbf   = (unsigned short*)(ws + 3 * SZ + SZ / 2); // bf16 [Mp][256]
  unsigned short* xbf   = qbf + SZ;                                // bf16 [Mp][256]
  unsigned short* wts   = (unsigned short*)(ws + 4 * SZ + SZ / 2);
  unsigned short* qwT  = wts;                    // [NL][384][256]
  unsigned short* valT = qwT + kNL * 384 * 256;  // [NL][256][256]
  unsigned short* outT = valT + kNL * 256 * 256;
  unsigned short* ff1T = outT + kNL * 256 * 256; // [NL][1024][256]
  unsigned short* ff2T = ff1T + kNL * 1024 * 256;// [NL][256][1024]
  float* qbias = (float*)(ff2T + kNL * 256 * 1024); // [NL][384]

  // --- weight prep ---
  wconv_k<<<dim3(256 / 32, 256 / 32, kNL), 256, 0, stream>>>(off_w, qwT, 256, 256, 0, 384);
  wconv_k<<<dim3(128 / 32, 256 / 32, kNL), 256, 0, stream>>>(aw_w,  qwT, 256, 128, 256, 384);
  wconv_k<<<dim3(256 / 32, 256 / 32, kNL), 256, 0, stream>>>(val_w, valT, 256, 256, 0, 256);
  wconv_k<<<dim3(256 / 32, 256 / 32, kNL), 256, 0, stream>>>(out_w, outT, 256, 256, 0, 256);
  wconv_k<<<dim3(1024 / 32, 256 / 32, kNL), 256, 0, stream>>>(ff1_w, ff1T, 256, 1024, 0, 1024);
  wconv_k<<<dim3(256 / 32, 1024 / 32, kNL), 256, 0, stream>>>(ff2_w, ff2T, 1024, 256, 0, 256);
  biaspack_k<<<(kNL * 384 + 255) / 256, 256, 0, stream>>>(off_b, aw_b, qbias);

  // --- build x0, pos, bf16 copies ---
  const int sides[4]  = {112, 56, 28, 14};
  const int starts[4] = {0, 12544, 15680, 16464};
  for (int l = 0; l < 4; ++l) {
    int HW = sides[l] * sides[l];
    dim3 g((HW + 31) / 32, kD / 32, kB);
    build_xpos_k<<<g, dim3(32, 8), 0, stream>>>(src[l], pos[l], lemb, xb, posb,
                                                xbf, qbf, HW, starts[l], l);
  }

  const dim3 blk(256);
  for (int i = 0; i < kNL; ++i) {
    // qout = (x+pos) @ [off_w | aw_w] + bias   (N=384)
    hgemm_k<0, 0, 0><<<dim3(3, kMT), blk, 0, stream>>>(
        qbf, qwT + (size_t)i * 384 * 256, qbias + i * 384, nullptr, qout, 384, 256);
    // val = x @ val_w + val_b  -> bf16
    hgemm_k<0, 0, 1><<<dim3(2, kMT), blk, 0, stream>>>(
        xbf, valT + (size_t)i * 256 * 256, val_b + i * 256, nullptr, valbf, 256, 256);
    // sampling (+softmax fused)
    msdeform_k<<<kM, blk, 0, stream>>>(valbf, qout, attbf);
    // x = x + attn @ out_w + out_b
    hgemm_k<0, 1, 0><<<dim3(2, kMT), blk, 0, stream>>>(
        attbf, outT + (size_t)i * 256 * 256, out_b + i * 256, xb, xb, 256, 256);
    layernorm_k<0><<<kM, blk, 0, stream>>>(xb, ln1_s + i * kD, ln1_b + i * kD,
                                           nullptr, xbf, nullptr);
    // ffmid = relu(x @ ff1_w + ff1_b) -> bf16
    hgemm_k<1, 0, 1><<<dim3(8, kMT), blk, 0, stream>>>(
        xbf, ff1T + (size_t)i * 1024 * 256, ff1_b + i * 1024, nullptr, ffbf, 1024, 256);
    // x = x + ffmid @ ff2_w + ff2_b
    hgemm_k<0, 1, 0><<<dim3(2, kMT), blk, 0, stream>>>(
        ffbf, ff2T + (size_t)i * 256 * 1024, ff2_b + i * 256, xb, xb, 256, 1024);
    layernorm_k<1><<<kM, blk, 0, stream>>>(xb, ln2_s + i * kD, ln2_b + i * kD,
                                           posb, xbf, qbf);
  }

  finalize_k<<<2048, blk, 0, stream>>>(xb, (float*)d_out);
}

// Round 3
// 1804.839 us; speedup vs baseline: 4.0167x; 1.6831x over previous
//
#include <hip/hip_runtime.h>

// MSDeformAttn Transformer encoder (Deformable-DETR), MI355X.
// Round 3: vectorized (ushort4) gather + 2-query blocks in msdeform_k.

constexpr int kB  = 2;
constexpr int kD  = 256;
constexpr int kNH = 8;
constexpr int kLV = 4;
constexpr int kNP = 4;
constexpr int kNL = 6;
constexpr int kDFF = 1024;
constexpr int kS  = 16660;                 // 112^2+56^2+28^2+14^2
constexpr int kM  = kB * kS;               // 33320
constexpr int kMp = 33408;                 // 261*128 (padded rows)
constexpr int kMT = kMp / 128;             // 261 row-tiles

typedef short bf16x8 __attribute__((ext_vector_type(8)));
typedef float f32x4  __attribute__((ext_vector_type(4)));

__device__ __forceinline__ unsigned short f2bf(float x) {
  union { float f; unsigned int u; } v; v.f = x;
  unsigned int r = v.u + 0x7FFFu + ((v.u >> 16) & 1u);
  return (unsigned short)(r >> 16);
}
__device__ __forceinline__ float bf2f(unsigned short u) {
  union { unsigned int u; float f; } v; v.u = ((unsigned int)u) << 16;
  return v.f;
}

#define GLOAD_LDS16(gp, lp)                                                    \
  __builtin_amdgcn_global_load_lds(                                            \
      (const __attribute__((address_space(1))) void*)(gp),                     \
      (__attribute__((address_space(3))) void*)(lp), 16, 0, 0)

// ---------------------------------------------------------------------------
// Input flatten+transpose; also emits bf16 x and bf16 q=x+pos.
// ---------------------------------------------------------------------------
__global__ __launch_bounds__(256) void build_xpos_k(
    const float* __restrict__ src, const float* __restrict__ pos,
    const float* __restrict__ lemb, float* __restrict__ xout,
    float* __restrict__ posout, unsigned short* __restrict__ xbf,
    unsigned short* __restrict__ qbf, int HW, int s0, int lvl)
{
  __shared__ float ts[32][33];
  __shared__ float tp[32][33];
  const int b  = blockIdx.z;
  const int p0 = blockIdx.x * 32, d0 = blockIdx.y * 32;
  const int tx = threadIdx.x, ty = threadIdx.y;   // (32, 8)
  for (int dd = ty; dd < 32; dd += 8) {
    int p = p0 + tx;
    if (p < HW) {
      size_t idx = ((size_t)b * kD + (d0 + dd)) * (size_t)HW + p;
      ts[dd][tx] = src[idx];
      tp[dd][tx] = pos[idx];
    }
  }
  __syncthreads();
  for (int pp = ty; pp < 32; pp += 8) {
    int p = p0 + pp, d = d0 + tx;
    if (p < HW) {
      size_t o = ((size_t)b * kS + (s0 + p)) * (size_t)kD + d;
      float x = ts[tx][pp];
      float pv = tp[tx][pp] + lemb[lvl * kD + d];
      xout[o] = x;
      posout[o] = pv;
      xbf[o] = f2bf(x);
      qbf[o] = f2bf(x + pv);
    }
  }
}

// ---------------------------------------------------------------------------
// Weight convert+transpose: W fp32 [NL][K][N] -> Wt bf16 [NL][rows][K] at rowoff
// ---------------------------------------------------------------------------
__global__ __launch_bounds__(256) void wconv_k(
    const float* __restrict__ W, unsigned short* __restrict__ Wt,
    int K, int N, int rowoff, int rowstotal)
{
  __shared__ float t[32][33];
  const int l = blockIdx.z;
  const int n0 = blockIdx.x * 32, k0 = blockIdx.y * 32;
  const int tx = threadIdx.x & 31, ty = threadIdx.x >> 5;
  const float* Wl = W + (size_t)l * K * N;
  unsigned short* Wtl = Wt + (size_t)l * rowstotal * K;
  for (int kk = ty; kk < 32; kk += 8)
    t[kk][tx] = Wl[(size_t)(k0 + kk) * N + n0 + tx];
  __syncthreads();
  for (int nn = ty; nn < 32; nn += 8)
    Wtl[(size_t)(rowoff + n0 + nn) * K + k0 + tx] = f2bf(t[tx][nn]);
}

__global__ __launch_bounds__(256) void biaspack_k(
    const float* __restrict__ ob, const float* __restrict__ ab,
    float* __restrict__ qb)
{
  int i = blockIdx.x * 256 + threadIdx.x;
  if (i >= kNL * 384) return;
  int l = i / 384, c = i - l * 384;
  qb[i] = (c < 256) ? ob[l * 256 + c] : ab[l * 128 + (c - 256)];
}

// ---------------------------------------------------------------------------
// bf16 MFMA GEMM: C[Mp,N] = A[Mp,K](bf16) @ Bt[N,K](bf16)^T + bias
// 128x128 tile, BK=32, 256 threads (4 waves, 2x2 of 64x64), m97 structure.
// ---------------------------------------------------------------------------
template<int RELU, int RES, int OUTBF>
__global__ __launch_bounds__(256) void hgemm_k(
    const unsigned short* __restrict__ A, const unsigned short* __restrict__ Bt,
    const float* __restrict__ bias, const float* __restrict__ Rsd,
    void* __restrict__ Cout, int N, int K)
{
  __shared__ unsigned short As[128 * 32];
  __shared__ unsigned short Bs[128 * 32];
  const int tid = threadIdx.x;
  const int bm = blockIdx.y * 128;
  const int bn = blockIdx.x * 128;
  const int lane = tid & 63;
  const int wave = tid >> 6;
  const int wr = (wave >> 1) * 64, wc = (wave & 1) * 64;
  const int l15 = lane & 15, l4 = lane >> 4;

  f32x4 acc[4][4] = {};

  const int c0 = tid, c1 = 256 + tid;
  const int r0 = c0 >> 2, kk0 = (c0 & 3) << 3;
  const int r1 = c1 >> 2, kk1 = (c1 & 3) << 3;
  const unsigned short* A0 = A + (size_t)(bm + r0) * K + kk0;
  const unsigned short* A1 = A + (size_t)(bm + r1) * K + kk1;
  const unsigned short* B0 = Bt + (size_t)(bn + r0) * K + kk0;
  const unsigned short* B1 = Bt + (size_t)(bn + r1) * K + kk1;

  for (int k0 = 0; k0 < K; k0 += 32) {
    GLOAD_LDS16(A0 + k0, (char*)As + c0 * 16);
    GLOAD_LDS16(A1 + k0, (char*)As + c1 * 16);
    GLOAD_LDS16(B0 + k0, (char*)Bs + c0 * 16);
    GLOAD_LDS16(B1 + k0, (char*)Bs + c1 * 16);
    __syncthreads();
    bf16x8 af[4], bfr[4];
#pragma unroll
    for (int m = 0; m < 4; ++m)
      af[m] = *(const bf16x8*)&As[(wr + m * 16 + l15) * 32 + l4 * 8];
#pragma unroll
    for (int n = 0; n < 4; ++n)
      bfr[n] = *(const bf16x8*)&Bs[(wc + n * 16 + l15) * 32 + l4 * 8];
#pragma unroll
    for (int m = 0; m < 4; ++m)
#pragma unroll
      for (int n = 0; n < 4; ++n)
        acc[m][n] = __builtin_amdgcn_mfma_f32_16x16x32_bf16(
            af[m], bfr[n], acc[m][n], 0, 0, 0);
    __syncthreads();
  }

#pragma unroll
  for (int n = 0; n < 4; ++n) {
    const int col = bn + wc + n * 16 + l15;
    const float bv = bias[col];
#pragma unroll
    for (int m = 0; m < 4; ++m) {
#pragma unroll
      for (int j = 0; j < 4; ++j) {
        const int row = bm + wr + m * 16 + l4 * 4 + j;
        float v = acc[m][n][j] + bv;
        if (RES) v += Rsd[(size_t)row * N + col];
        if (RELU) v = fmaxf(v, 0.f);
        if (OUTBF)
          ((unsigned short*)Cout)[(size_t)row * N + col] = f2bf(v);
        else
          ((float*)Cout)[(size_t)row * N + col] = v;
      }
    }
  }
}

// ---------------------------------------------------------------------------
// MS deformable attention sampling (+fused softmax), 2 queries per block.
// Phase 1: 256 threads = 2 queries x 128 (h,l,p) corners: softmax + bilinear
//          indices/weights -> LDS.
// Phase 2: thread = (h, cg, l8): for each query, 16 ushort4 gathers (8B),
//          partial sums over its corner group; LDS reduce over cg.
// ---------------------------------------------------------------------------
__global__ __launch_bounds__(256) void msdeform_k(
    const unsigned short* __restrict__ val, const float* __restrict__ qout,
    unsigned short* __restrict__ outbf)
{
  __shared__ int   sIdx[2][4][128];
  __shared__ float sW[2][4][128];
  __shared__ float sRed[2][8][8][4][4];   // [q][h][l8][j][cg]
  const int bs0 = blockIdx.x * 2;
  const int tid = threadIdx.x;

  {
    const int q = tid >> 7;          // 0..1
    const int t = tid & 127;         // corner id = h*16 + l*4 + p
    const int bs = bs0 + q;
    const int b = bs / kS, s = bs - b * kS;
    const int l = (t & 15) >> 2;

    // softmax over the 16-corner group (lanes t aligned to 16 within wave)
    const float logit = qout[(size_t)bs * 384 + 256 + t];
    float mx = logit;
#pragma unroll
    for (int d2 = 1; d2 < 16; d2 <<= 1) mx = fmaxf(mx, __shfl_xor(mx, d2, 64));
    float e = __expf(logit - mx);
    float sm = e;
#pragma unroll
    for (int d2 = 1; d2 < 16; d2 <<= 1) sm += __shfl_xor(sm, d2, 64);
    const float a = e / sm;

    // reference point
    int ls, sideq;
    if (s < 12544)      { ls = s;         sideq = 112; }
    else if (s < 15680) { ls = s - 12544; sideq = 56;  }
    else if (s < 16464) { ls = s - 15680; sideq = 28;  }
    else                { ls = s - 16464; sideq = 14;  }
    const float rx = ((ls % sideq) + 0.5f) / (float)sideq;
    const float ry = ((ls / sideq) + 0.5f) / (float)sideq;

    const int side  = 112 >> l;
    const int start = (l >= 1 ? 12544 : 0) + (l >= 2 ? 3136 : 0) + (l >= 3 ? 784 : 0);
    const float ox = qout[(size_t)bs * 384 + t * 2 + 0];
    const float oy = qout[(size_t)bs * 384 + t * 2 + 1];
    const float xx = rx * side + ox - 0.5f;
    const float yy = ry * side + oy - 0.5f;
    const float xf = floorf(xx), yf = floorf(yy);
    const float lx = xx - xf, ly = yy - yf;
    const int x0 = (int)xf, y0 = (int)yf;
    const float w00 = (1.f - lx) * (1.f - ly) * a, w10 = lx * (1.f - ly) * a;
    const float w01 = (1.f - lx) * ly * a,         w11 = lx * ly * a;
    const bool xv0 = (unsigned)x0 < (unsigned)side, xv1 = (unsigned)(x0 + 1) < (unsigned)side;
    const bool yv0 = (unsigned)y0 < (unsigned)side, yv1 = (unsigned)(y0 + 1) < (unsigned)side;
    const int cx0 = min(max(x0, 0), side - 1), cx1 = min(max(x0 + 1, 0), side - 1);
    const int cy0 = min(max(y0, 0), side - 1), cy1 = min(max(y0 + 1, 0), side - 1);
    const int rowbase = b * kS + start;
    sIdx[q][0][t] = rowbase + cy0 * side + cx0;
    sIdx[q][1][t] = rowbase + cy0 * side + cx1;
    sIdx[q][2][t] = rowbase + cy1 * side + cx0;
    sIdx[q][3][t] = rowbase + cy1 * side + cx1;
    sW[q][0][t] = (xv0 && yv0) ? w00 : 0.f;
    sW[q][1][t] = (xv1 && yv0) ? w10 : 0.f;
    sW[q][2][t] = (xv0 && yv1) ? w01 : 0.f;
    sW[q][3][t] = (xv1 && yv1) ? w11 : 0.f;
  }
  __syncthreads();

  const int h  = tid >> 5;           // 0..7
  const int cg = (tid >> 3) & 3;     // corner group 0..3
  const int l8 = tid & 7;            // 8B lane: dh = l8*4 .. l8*4+3
  const unsigned short* vb = val + h * 32 + l8 * 4;

  float acc[2][4] = {};
#pragma unroll
  for (int q = 0; q < 2; ++q) {
#pragma unroll
    for (int sp = 0; sp < 16; ++sp) {
      const int t = (h << 4) + sp;
      const int r = sIdx[q][cg][t];
      const float w = sW[q][cg][t];
      const ushort4 v4 = *(const ushort4*)(vb + (size_t)r * 256);
      acc[q][0] = fmaf(w, bf2f(v4.x), acc[q][0]);
      acc[q][1] = fmaf(w, bf2f(v4.y), acc[q][1]);
      acc[q][2] = fmaf(w, bf2f(v4.z), acc[q][2]);
      acc[q][3] = fmaf(w, bf2f(v4.w), acc[q][3]);
    }
  }
#pragma unroll
  for (int q = 0; q < 2; ++q)
#pragma unroll
    for (int j = 0; j < 4; ++j)
      sRed[q][h][l8][j][cg] = acc[q][j];
  __syncthreads();

  const int dh = tid & 31;
#pragma unroll
  for (int q = 0; q < 2; ++q) {
    const float4 v = *(const float4*)&sRed[q][h][dh >> 2][dh & 3][0];
    outbf[(size_t)(bs0 + q) * 256 + h * 32 + dh] = f2bf(v.x + v.y + v.z + v.w);
  }
}

// ---------------------------------------------------------------------------
// In-place LayerNorm over D=256 + bf16 x (and optional bf16 q=x+pos) emit.
// ---------------------------------------------------------------------------
template<int WQ>
__global__ __launch_bounds__(256) void layernorm_k(
    float* __restrict__ x, const float* __restrict__ g,
    const float* __restrict__ bta, const float* __restrict__ posb,
    unsigned short* __restrict__ xbf, unsigned short* __restrict__ qbf)
{
  const int row = blockIdx.x;
  const int t = threadIdx.x;
  float* p = x + (size_t)row * kD;
  float v = p[t];
  __shared__ float red[4];
  float sacc = v;
#pragma unroll
  for (int m = 1; m <= 32; m <<= 1) sacc += __shfl_xor(sacc, m, 64);
  if ((t & 63) == 0) red[t >> 6] = sacc;
  __syncthreads();
  const float mean = (red[0] + red[1] + red[2] + red[3]) * (1.0f / kD);
  __syncthreads();
  const float dv = v - mean;
  float s2 = dv * dv;
#pragma unroll
  for (int m = 1; m <= 32; m <<= 1) s2 += __shfl_xor(s2, m, 64);
  if ((t & 63) == 0) red[t >> 6] = s2;
  __syncthreads();
  const float var = (red[0] + red[1] + red[2] + red[3]) * (1.0f / kD);
  const float inv = 1.0f / sqrtf(var + 1e-5f);
  const float y = dv * inv * g[t] + bta[t];
  p[t] = y;
  xbf[(size_t)row * kD + t] = f2bf(y);
  if (WQ) qbf[(size_t)row * kD + t] = f2bf(y + posb[(size_t)row * kD + t]);
}

// ---------------------------------------------------------------------------
__global__ __launch_bounds__(256) void finalize_k(
    const float* __restrict__ x, float* __restrict__ out)
{
  const size_t n = (size_t)kM * kD;
  for (size_t i = (size_t)blockIdx.x * blockDim.x + threadIdx.x; i < n;
       i += (size_t)gridDim.x * blockDim.x)
    out[i] = x[i];
  if (blockIdx.x == 0 && threadIdx.x == 0) {
    out[n + 0] = 112.f; out[n + 1] = 112.f;
    out[n + 2] = 56.f;  out[n + 3] = 56.f;
    out[n + 4] = 28.f;  out[n + 5] = 28.f;
    out[n + 6] = 14.f;  out[n + 7] = 14.f;
    out[n + 8] = 0.f;   out[n + 9] = 12544.f;
    out[n + 10] = 15680.f; out[n + 11] = 16464.f;
  }
}

// ---------------------------------------------------------------------------
extern "C" void kernel_launch(void* const* d_in, const int* in_sizes, int n_in,
                              void* d_out, int out_size, void* d_ws, size_t ws_size,
                              hipStream_t stream)
{
  const float* src[4] = {(const float*)d_in[0], (const float*)d_in[2],
                         (const float*)d_in[4], (const float*)d_in[6]};
  const float* pos[4] = {(const float*)d_in[1], (const float*)d_in[3],
                         (const float*)d_in[5], (const float*)d_in[7]};
  const float* lemb  = (const float*)d_in[8];
  const float* off_w = (const float*)d_in[9];
  const float* off_b = (const float*)d_in[10];
  const float* aw_w  = (const float*)d_in[11];
  const float* aw_b  = (const float*)d_in[12];
  const float* val_w = (const float*)d_in[13];
  const float* val_b = (const float*)d_in[14];
  const float* out_w = (const float*)d_in[15];
  const float* out_b = (const float*)d_in[16];
  const float* ln1_s = (const float*)d_in[17];
  const float* ln1_b = (const float*)d_in[18];
  const float* ff1_w = (const float*)d_in[19];
  const float* ff1_b = (const float*)d_in[20];
  const float* ff2_w = (const float*)d_in[21];
  const float* ff2_b = (const float*)d_in[22];
  const float* ln2_s = (const float*)d_in[23];
  const float* ln2_b = (const float*)d_in[24];

  const size_t SZ = (size_t)kMp * kD;      // 8,552,448 floats
  float* ws   = (float*)d_ws;
  float* posb = (float*)d_out;             // pos lives in d_out until finalize
  float* xb   = ws;                        // fp32 [SZ]
  float* R    = ws + SZ;                   // reusable region [2.5*SZ floats]
  float* qout = R;                         // fp32 [Mp][384] = 1.5*SZ
  unsigned short* valbf = (unsigned short*)(R + SZ + SZ / 2);  // bf16 [Mp][256]
  unsigned short* attbf = (unsigned short*)(R + 2 * SZ);       // bf16 [Mp][256]
  unsigned short* ffbf  = (unsigned short*)R;                  // bf16 [Mp][1024]
  unsigned short* qbf   = (unsigned short*)(ws + 3 * SZ + SZ / 2); // bf16 [Mp][256]
  unsigned short* xbf   = qbf + SZ;                                // bf16 [Mp][256]
  unsigned short* wts   = (unsigned short*)(ws + 4 * SZ + SZ / 2);
  unsigned short* qwT  = wts;                    // [NL][384][256]
  unsigned short* valT = qwT + kNL * 384 * 256;  // [NL][256][256]
  unsigned short* outT = valT + kNL * 256 * 256;
  unsigned short* ff1T = outT + kNL * 256 * 256; // [NL][1024][256]
  unsigned short* ff2T = ff1T + kNL * 1024 * 256;// [NL][256][1024]
  float* qbias = (float*)(ff2T + kNL * 256 * 1024); // [NL][384]

  // --- weight prep ---
  wconv_k<<<dim3(256 / 32, 256 / 32, kNL), 256, 0, stream>>>(off_w, qwT, 256, 256, 0, 384);
  wconv_k<<<dim3(128 / 32, 256 / 32, kNL), 256, 0, stream>>>(aw_w,  qwT, 256, 128, 256, 384);
  wconv_k<<<dim3(256 / 32, 256 / 32, kNL), 256, 0, stream>>>(val_w, valT, 256, 256, 0, 256);
  wconv_k<<<dim3(256 / 32, 256 / 32, kNL), 256, 0, stream>>>(out_w, outT, 256, 256, 0, 256);
  wconv_k<<<dim3(1024 / 32, 256 / 32, kNL), 256, 0, stream>>>(ff1_w, ff1T, 256, 1024, 0, 1024);
  wconv_k<<<dim3(256 / 32, 1024 / 32, kNL), 256, 0, stream>>>(ff2_w, ff2T, 1024, 256, 0, 256);
  biaspack_k<<<(kNL * 384 + 255) / 256, 256, 0, stream>>>(off_b, aw_b, qbias);

  // --- build x0, pos, bf16 copies ---
  const int sides[4]  = {112, 56, 28, 14};
  const int starts[4] = {0, 12544, 15680, 16464};
  for (int l = 0; l < 4; ++l) {
    int HW = sides[l] * sides[l];
    dim3 g((HW + 31) / 32, kD / 32, kB);
    build_xpos_k<<<g, dim3(32, 8), 0, stream>>>(src[l], pos[l], lemb, xb, posb,
                                                xbf, qbf, HW, starts[l], l);
  }

  const dim3 blk(256);
  for (int i = 0; i < kNL; ++i) {
    // qout = (x+pos) @ [off_w | aw_w] + bias   (N=384)
    hgemm_k<0, 0, 0><<<dim3(3, kMT), blk, 0, stream>>>(
        qbf, qwT + (size_t)i * 384 * 256, qbias + i * 384, nullptr, qout, 384, 256);
    // val = x @ val_w + val_b  -> bf16
    hgemm_k<0, 0, 1><<<dim3(2, kMT), blk, 0, stream>>>(
        xbf, valT + (size_t)i * 256 * 256, val_b + i * 256, nullptr, valbf, 256, 256);
    // sampling (+softmax fused)
    msdeform_k<<<kM / 2, blk, 0, stream>>>(valbf, qout, attbf);
    // x = x + attn @ out_w + out_b
    hgemm_k<0, 1, 0><<<dim3(2, kMT), blk, 0, stream>>>(
        attbf, outT + (size_t)i * 256 * 256, out_b + i * 256, xb, xb, 256, 256);
    layernorm_k<0><<<kM, blk, 0, stream>>>(xb, ln1_s + i * kD, ln1_b + i * kD,
                                           nullptr, xbf, nullptr);
    // ffmid = relu(x @ ff1_w + ff1_b) -> bf16
    hgemm_k<1, 0, 1><<<dim3(8, kMT), blk, 0, stream>>>(
        xbf, ff1T + (size_t)i * 1024 * 256, ff1_b + i * 1024, nullptr, ffbf, 1024, 256);
    // x = x + ffmid @ ff2_w + ff2_b
    hgemm_k<0, 1, 0><<<dim3(2, kMT), blk, 0, stream>>>(
        ffbf, ff2T + (size_t)i * 256 * 1024, ff2_b + i * 256, xb, xb, 256, 1024);
    layernorm_k<1><<<kM, blk, 0, stream>>>(xb, ln2_s + i * kD, ln2_b + i * kD,
                                           posb, xbf, qbf);
  }

  finalize_k<<<2048, blk, 0, stream>>>(xb, (float*)d_out);
}

// Round 4
// 1736.914 us; speedup vs baseline: 4.1738x; 1.0391x over previous
//
#include <hip/hip_runtime.h>

// MSDeformAttn Transformer encoder (Deformable-DETR), MI355X.
// Round 4: conflict-free msdeform (in-register corner accum, 4 q/block),
//          LN fused into out-proj & ff2 GEMMs (BN=256 full-row tiles),
//          last layer writes d_out directly.

constexpr int kB  = 2;
constexpr int kD  = 256;
constexpr int kNH = 8;
constexpr int kLV = 4;
constexpr int kNP = 4;
constexpr int kNL = 6;
constexpr int kDFF = 1024;
constexpr int kS  = 16660;                 // 112^2+56^2+28^2+14^2
constexpr int kM  = kB * kS;               // 33320
constexpr int kMp = 33408;                 // 261*128 (padded rows)
constexpr int kMT = kMp / 128;             // 261 row-tiles

typedef short bf16x8 __attribute__((ext_vector_type(8)));
typedef float f32x4  __attribute__((ext_vector_type(4)));

__device__ __forceinline__ unsigned short f2bf(float x) {
  union { float f; unsigned int u; } v; v.f = x;
  unsigned int r = v.u + 0x7FFFu + ((v.u >> 16) & 1u);
  return (unsigned short)(r >> 16);
}
__device__ __forceinline__ float bf2f(unsigned short u) {
  union { unsigned int u; float f; } v; v.u = ((unsigned int)u) << 16;
  return v.f;
}

#define GLOAD_LDS16(gp, lp)                                                    \
  __builtin_amdgcn_global_load_lds(                                            \
      (const __attribute__((address_space(1))) void*)(gp),                     \
      (__attribute__((address_space(3))) void*)(lp), 16, 0, 0)

// ---------------------------------------------------------------------------
// Input flatten+transpose; also emits bf16 x and bf16 q=x+pos.
// ---------------------------------------------------------------------------
__global__ __launch_bounds__(256) void build_xpos_k(
    const float* __restrict__ src, const float* __restrict__ pos,
    const float* __restrict__ lemb, float* __restrict__ xout,
    float* __restrict__ posout, unsigned short* __restrict__ xbf,
    unsigned short* __restrict__ qbf, int HW, int s0, int lvl)
{
  __shared__ float ts[32][33];
  __shared__ float tp[32][33];
  const int b  = blockIdx.z;
  const int p0 = blockIdx.x * 32, d0 = blockIdx.y * 32;
  const int tx = threadIdx.x, ty = threadIdx.y;   // (32, 8)
  for (int dd = ty; dd < 32; dd += 8) {
    int p = p0 + tx;
    if (p < HW) {
      size_t idx = ((size_t)b * kD + (d0 + dd)) * (size_t)HW + p;
      ts[dd][tx] = src[idx];
      tp[dd][tx] = pos[idx];
    }
  }
  __syncthreads();
  for (int pp = ty; pp < 32; pp += 8) {
    int p = p0 + pp, d = d0 + tx;
    if (p < HW) {
      size_t o = ((size_t)b * kS + (s0 + p)) * (size_t)kD + d;
      float x = ts[tx][pp];
      float pv = tp[tx][pp] + lemb[lvl * kD + d];
      xout[o] = x;
      posout[o] = pv;
      xbf[o] = f2bf(x);
      qbf[o] = f2bf(x + pv);
    }
  }
}

// ---------------------------------------------------------------------------
// Weight convert+transpose: W fp32 [NL][K][N] -> Wt bf16 [NL][rows][K] at rowoff
// ---------------------------------------------------------------------------
__global__ __launch_bounds__(256) void wconv_k(
    const float* __restrict__ W, unsigned short* __restrict__ Wt,
    int K, int N, int rowoff, int rowstotal)
{
  __shared__ float t[32][33];
  const int l = blockIdx.z;
  const int n0 = blockIdx.x * 32, k0 = blockIdx.y * 32;
  const int tx = threadIdx.x & 31, ty = threadIdx.x >> 5;
  const float* Wl = W + (size_t)l * K * N;
  unsigned short* Wtl = Wt + (size_t)l * rowstotal * K;
  for (int kk = ty; kk < 32; kk += 8)
    t[kk][tx] = Wl[(size_t)(k0 + kk) * N + n0 + tx];
  __syncthreads();
  for (int nn = ty; nn < 32; nn += 8)
    Wtl[(size_t)(rowoff + n0 + nn) * K + k0 + tx] = f2bf(t[tx][nn]);
}

__global__ __launch_bounds__(256) void biaspack_k(
    const float* __restrict__ ob, const float* __restrict__ ab,
    float* __restrict__ qb)
{
  int i = blockIdx.x * 256 + threadIdx.x;
  if (i >= kNL * 384) return;
  int l = i / 384, c = i - l * 384;
  qb[i] = (c < 256) ? ob[l * 256 + c] : ab[l * 128 + (c - 256)];
}

// ---------------------------------------------------------------------------
// bf16 MFMA GEMM: C[Mp,N] = A[Mp,K](bf16) @ Bt[N,K](bf16)^T + bias
// 128x128 tile, BK=32, 256 threads (4 waves, 2x2 of 64x64), m97 structure.
// ---------------------------------------------------------------------------
template<int RELU, int OUTBF>
__global__ __launch_bounds__(256) void hgemm_k(
    const unsigned short* __restrict__ A, const unsigned short* __restrict__ Bt,
    const float* __restrict__ bias, void* __restrict__ Cout, int N, int K)
{
  __shared__ unsigned short As[128 * 32];
  __shared__ unsigned short Bs[128 * 32];
  const int tid = threadIdx.x;
  const int bm = blockIdx.y * 128;
  const int bn = blockIdx.x * 128;
  const int lane = tid & 63;
  const int wave = tid >> 6;
  const int wr = (wave >> 1) * 64, wc = (wave & 1) * 64;
  const int l15 = lane & 15, l4 = lane >> 4;

  f32x4 acc[4][4] = {};

  const int c0 = tid, c1 = 256 + tid;
  const int r0 = c0 >> 2, kk0 = (c0 & 3) << 3;
  const int r1 = c1 >> 2, kk1 = (c1 & 3) << 3;
  const unsigned short* A0 = A + (size_t)(bm + r0) * K + kk0;
  const unsigned short* A1 = A + (size_t)(bm + r1) * K + kk1;
  const unsigned short* B0 = Bt + (size_t)(bn + r0) * K + kk0;
  const unsigned short* B1 = Bt + (size_t)(bn + r1) * K + kk1;

  for (int k0 = 0; k0 < K; k0 += 32) {
    GLOAD_LDS16(A0 + k0, (char*)As + c0 * 16);
    GLOAD_LDS16(A1 + k0, (char*)As + c1 * 16);
    GLOAD_LDS16(B0 + k0, (char*)Bs + c0 * 16);
    GLOAD_LDS16(B1 + k0, (char*)Bs + c1 * 16);
    __syncthreads();
    bf16x8 af[4], bfr[4];
#pragma unroll
    for (int m = 0; m < 4; ++m)
      af[m] = *(const bf16x8*)&As[(wr + m * 16 + l15) * 32 + l4 * 8];
#pragma unroll
    for (int n = 0; n < 4; ++n)
      bfr[n] = *(const bf16x8*)&Bs[(wc + n * 16 + l15) * 32 + l4 * 8];
#pragma unroll
    for (int m = 0; m < 4; ++m)
#pragma unroll
      for (int n = 0; n < 4; ++n)
        acc[m][n] = __builtin_amdgcn_mfma_f32_16x16x32_bf16(
            af[m], bfr[n], acc[m][n], 0, 0, 0);
    __syncthreads();
  }

#pragma unroll
  for (int n = 0; n < 4; ++n) {
    const int col = bn + wc + n * 16 + l15;
    const float bv = bias[col];
#pragma unroll
    for (int m = 0; m < 4; ++m) {
#pragma unroll
      for (int j = 0; j < 4; ++j) {
        const int row = bm + wr + m * 16 + l4 * 4 + j;
        float v = acc[m][n][j] + bv;
        if (RELU) v = fmaxf(v, 0.f);
        if (OUTBF)
          ((unsigned short*)Cout)[(size_t)row * N + col] = f2bf(v);
        else
          ((float*)Cout)[(size_t)row * N + col] = v;
      }
    }
  }
}

// ---------------------------------------------------------------------------
// bf16 MFMA GEMM with fused bias+residual+LayerNorm epilogue.
// BM=128, BN=256 (= full row), BK=32, 512 threads (8 waves, 2x4 of 64x64).
// OUTDST=0: write y->xb fp32 + xbf bf16 (+qbf=y+pos if WQ). OUTDST=1: y->dout.
// ---------------------------------------------------------------------------
template<int WQ, int OUTDST>
__global__ __launch_bounds__(512) void hgemmln_k(
    const unsigned short* __restrict__ A, const unsigned short* __restrict__ Bt,
    const float* __restrict__ bias, const float* __restrict__ Rsd,
    const float* __restrict__ g, const float* __restrict__ beta,
    const float* __restrict__ posb, float* __restrict__ yout,
    unsigned short* __restrict__ xbf, unsigned short* __restrict__ qbf, int K)
{
  __shared__ unsigned short As[128 * 32];
  __shared__ unsigned short Bs[256 * 32];
  __shared__ float ssum[128][5];
  __shared__ float ssq[128][5];
  const int tid = threadIdx.x;
  const int bm = blockIdx.x * 128;
  const int lane = tid & 63;
  const int wave = tid >> 6;
  const int wr = (wave >> 2) * 64, wc = (wave & 3) * 64;
  const int l15 = lane & 15, l4 = lane >> 4;

  f32x4 acc[4][4] = {};

  const int ra = tid >> 2, ka = (tid & 3) << 3;
  const unsigned short* A0 = A + (size_t)(bm + ra) * K + ka;
  const int cb1 = 512 + tid;
  const int rb0 = tid >> 2, kb0 = (tid & 3) << 3;
  const int rb1 = cb1 >> 2, kb1 = (cb1 & 3) << 3;
  const unsigned short* B0 = Bt + (size_t)rb0 * K + kb0;
  const unsigned short* B1 = Bt + (size_t)rb1 * K + kb1;

  for (int k0 = 0; k0 < K; k0 += 32) {
    GLOAD_LDS16(A0 + k0, (char*)As + tid * 16);
    GLOAD_LDS16(B0 + k0, (char*)Bs + tid * 16);
    GLOAD_LDS16(B1 + k0, (char*)Bs + cb1 * 16);
    __syncthreads();
    bf16x8 af[4], bfr[4];
#pragma unroll
    for (int m = 0; m < 4; ++m)
      af[m] = *(const bf16x8*)&As[(wr + m * 16 + l15) * 32 + l4 * 8];
#pragma unroll
    for (int n = 0; n < 4; ++n)
      bfr[n] = *(const bf16x8*)&Bs[(wc + n * 16 + l15) * 32 + l4 * 8];
#pragma unroll
    for (int m = 0; m < 4; ++m)
#pragma unroll
      for (int n = 0; n < 4; ++n)
        acc[m][n] = __builtin_amdgcn_mfma_f32_16x16x32_bf16(
            af[m], bfr[n], acc[m][n], 0, 0, 0);
    __syncthreads();
  }

  // epilogue: v = acc + bias + residual (in regs)
  float bv[4], gv[4], btv[4];
#pragma unroll
  for (int n = 0; n < 4; ++n) {
    const int col = wc + n * 16 + l15;
    bv[n] = bias[col];
    gv[n] = g[col];
    btv[n] = beta[col];
  }
#pragma unroll
  for (int m = 0; m < 4; ++m) {
#pragma unroll
    for (int j = 0; j < 4; ++j) {
      const int row = bm + wr + m * 16 + l4 * 4 + j;
#pragma unroll
      for (int n = 0; n < 4; ++n)
        acc[m][n][j] += bv[n] + Rsd[(size_t)row * kD + wc + n * 16 + l15];
    }
  }
  // per-row partial sums over this wave's 64 cols, reduce over 16-lane group
#pragma unroll
  for (int m = 0; m < 4; ++m) {
#pragma unroll
    for (int j = 0; j < 4; ++j) {
      float s = acc[m][0][j] + acc[m][1][j] + acc[m][2][j] + acc[m][3][j];
      float q = acc[m][0][j] * acc[m][0][j] + acc[m][1][j] * acc[m][1][j] +
                acc[m][2][j] * acc[m][2][j] + acc[m][3][j] * acc[m][3][j];
#pragma unroll
      for (int d2 = 1; d2 < 16; d2 <<= 1) {
        s += __shfl_xor(s, d2, 64);
        q += __shfl_xor(q, d2, 64);
      }
      if (l15 == 0) {
        const int r = wr + m * 16 + l4 * 4 + j;
        ssum[r][wave & 3] = s;
        ssq[r][wave & 3] = q;
      }
    }
  }
  __syncthreads();
#pragma unroll
  for (int m = 0; m < 4; ++m) {
#pragma unroll
    for (int j = 0; j < 4; ++j) {
      const int r = wr + m * 16 + l4 * 4 + j;
      const int row = bm + r;
      const float mean = (ssum[r][0] + ssum[r][1] + ssum[r][2] + ssum[r][3]) *
                         (1.0f / kD);
      const float var = (ssq[r][0] + ssq[r][1] + ssq[r][2] + ssq[r][3]) *
                        (1.0f / kD) - mean * mean;
      const float rstd = rsqrtf(var + 1e-5f);
      if (row < kM) {
#pragma unroll
        for (int n = 0; n < 4; ++n) {
          const int col = wc + n * 16 + l15;
          const float y = (acc[m][n][j] - mean) * rstd * gv[n] + btv[n];
          const size_t o = (size_t)row * kD + col;
          if (OUTDST) {
            yout[o] = y;
          } else {
            yout[o] = y;
            xbf[o] = f2bf(y);
            if (WQ) qbf[o] = f2bf(y + posb[o]);
          }
        }
      }
    }
  }
}

// ---------------------------------------------------------------------------
// MS deformable attention sampling (+fused softmax), 4 queries per block.
// Phase 1: 512 items = 4 q x 128 corners (2/thread): softmax + bilinear
//          idx/weight -> LDS at t' = sp*8 + h (conflict-free gather reads).
// Phase 2: thread = (q=wave, h, l8): 64 ushort4 gathers, all 4 corners
//          accumulate in registers, direct ushort4 store.
// ---------------------------------------------------------------------------
__global__ __launch_bounds__(256) void msdeform_k(
    const unsigned short* __restrict__ val, const float* __restrict__ qout,
    unsigned short* __restrict__ outbf)
{
  __shared__ int   sIdx[4][4][128];   // [corner][q][sp*8+h]
  __shared__ float sW[4][4][128];
  const int bs0 = blockIdx.x * 4;
  const int tid = threadIdx.x;

#pragma unroll
  for (int it = 0; it < 2; ++it) {
    const int item = tid + it * 256;
    const int q = item >> 7;         // 0..3
    const int t = item & 127;        // h*16 + l*4 + p
    const int bs = bs0 + q;
    const int b = bs / kS, s = bs - b * kS;
    const int l = (t & 15) >> 2;

    const float logit = qout[(size_t)bs * 384 + 256 + t];
    float mx = logit;
#pragma unroll
    for (int d2 = 1; d2 < 16; d2 <<= 1) mx = fmaxf(mx, __shfl_xor(mx, d2, 64));
    float e = __expf(logit - mx);
    float sm = e;
#pragma unroll
    for (int d2 = 1; d2 < 16; d2 <<= 1) sm += __shfl_xor(sm, d2, 64);
    const float a = e / sm;

    int ls, sideq;
    if (s < 12544)      { ls = s;         sideq = 112; }
    else if (s < 15680) { ls = s - 12544; sideq = 56;  }
    else if (s < 16464) { ls = s - 15680; sideq = 28;  }
    else                { ls = s - 16464; sideq = 14;  }
    const float rx = ((ls % sideq) + 0.5f) / (float)sideq;
    const float ry = ((ls / sideq) + 0.5f) / (float)sideq;

    const int side  = 112 >> l;
    const int start = (l >= 1 ? 12544 : 0) + (l >= 2 ? 3136 : 0) + (l >= 3 ? 784 : 0);
    const float ox = qout[(size_t)bs * 384 + t * 2 + 0];
    const float oy = qout[(size_t)bs * 384 + t * 2 + 1];
    const float xx = rx * side + ox - 0.5f;
    const float yy = ry * side + oy - 0.5f;
    const float xf = floorf(xx), yf = floorf(yy);
    const float lx = xx - xf, ly = yy - yf;
    const int x0 = (int)xf, y0 = (int)yf;
    const float w00 = (1.f - lx) * (1.f - ly) * a, w10 = lx * (1.f - ly) * a;
    const float w01 = (1.f - lx) * ly * a,         w11 = lx * ly * a;
    const bool xv0 = (unsigned)x0 < (unsigned)side, xv1 = (unsigned)(x0 + 1) < (unsigned)side;
    const bool yv0 = (unsigned)y0 < (unsigned)side, yv1 = (unsigned)(y0 + 1) < (unsigned)side;
    const int cx0 = min(max(x0, 0), side - 1), cx1 = min(max(x0 + 1, 0), side - 1);
    const int cy0 = min(max(y0, 0), side - 1), cy1 = min(max(y0 + 1, 0), side - 1);
    const int rowbase = b * kS + start;
    const int t2 = (t & 15) * 8 + (t >> 4);   // sp*8 + h
    sIdx[0][q][t2] = rowbase + cy0 * side + cx0;
    sIdx[1][q][t2] = rowbase + cy0 * side + cx1;
    sIdx[2][q][t2] = rowbase + cy1 * side + cx0;
    sIdx[3][q][t2] = rowbase + cy1 * side + cx1;
    sW[0][q][t2] = (xv0 && yv0) ? w00 : 0.f;
    sW[1][q][t2] = (xv1 && yv0) ? w10 : 0.f;
    sW[2][q][t2] = (xv0 && yv1) ? w01 : 0.f;
    sW[3][q][t2] = (xv1 && yv1) ? w11 : 0.f;
  }
  __syncthreads();

  const int q  = tid >> 6;          // wave = query
  const int h  = (tid >> 3) & 7;
  const int l8 = tid & 7;
  const unsigned short* vb = val + h * 32 + l8 * 4;

  float a0 = 0.f, a1 = 0.f, a2 = 0.f, a3 = 0.f;
#pragma unroll
  for (int sp = 0; sp < 16; ++sp) {
    const int t2 = sp * 8 + h;
#pragma unroll
    for (int c = 0; c < 4; ++c) {
      const int r = sIdx[c][q][t2];
      const float w = sW[c][q][t2];
      const ushort4 v4 = *(const ushort4*)(vb + (size_t)r * 256);
      a0 = fmaf(w, bf2f(v4.x), a0);
      a1 = fmaf(w, bf2f(v4.y), a1);
      a2 = fmaf(w, bf2f(v4.z), a2);
      a3 = fmaf(w, bf2f(v4.w), a3);
    }
  }
  ushort4 o;
  o.x = f2bf(a0); o.y = f2bf(a1); o.z = f2bf(a2); o.w = f2bf(a3);
  *(ushort4*)(outbf + (size_t)(bs0 + q) * 256 + h * 32 + l8 * 4) = o;
}

// ---------------------------------------------------------------------------
__global__ void tail_k(float* __restrict__ out)
{
  if (threadIdx.x == 0) {
    const size_t n = (size_t)kM * kD;
    out[n + 0] = 112.f; out[n + 1] = 112.f;
    out[n + 2] = 56.f;  out[n + 3] = 56.f;
    out[n + 4] = 28.f;  out[n + 5] = 28.f;
    out[n + 6] = 14.f;  out[n + 7] = 14.f;
    out[n + 8] = 0.f;   out[n + 9] = 12544.f;
    out[n + 10] = 15680.f; out[n + 11] = 16464.f;
  }
}

// ---------------------------------------------------------------------------
extern "C" void kernel_launch(void* const* d_in, const int* in_sizes, int n_in,
                              void* d_out, int out_size, void* d_ws, size_t ws_size,
                              hipStream_t stream)
{
  const float* src[4] = {(const float*)d_in[0], (const float*)d_in[2],
                         (const float*)d_in[4], (const float*)d_in[6]};
  const float* pos[4] = {(const float*)d_in[1], (const float*)d_in[3],
                         (const float*)d_in[5], (const float*)d_in[7]};
  const float* lemb  = (const float*)d_in[8];
  const float* off_w = (const float*)d_in[9];
  const float* off_b = (const float*)d_in[10];
  const float* aw_w  = (const float*)d_in[11];
  const float* aw_b  = (const float*)d_in[12];
  const float* val_w = (const float*)d_in[13];
  const float* val_b = (const float*)d_in[14];
  const float* out_w = (const float*)d_in[15];
  const float* out_b = (const float*)d_in[16];
  const float* ln1_s = (const float*)d_in[17];
  const float* ln1_b = (const float*)d_in[18];
  const float* ff1_w = (const float*)d_in[19];
  const float* ff1_b = (const float*)d_in[20];
  const float* ff2_w = (const float*)d_in[21];
  const float* ff2_b = (const float*)d_in[22];
  const float* ln2_s = (const float*)d_in[23];
  const float* ln2_b = (const float*)d_in[24];

  const size_t SZ = (size_t)kMp * kD;      // 8,552,448 floats
  float* ws   = (float*)d_ws;
  float* posb = (float*)d_out;             // pos lives in d_out until last layer
  float* xb   = ws;                        // fp32 [SZ]
  float* R    = ws + SZ;                   // reusable region
  float* qout = R;                         // fp32 [Mp][384] = 1.5*SZ
  unsigned short* valbf = (unsigned short*)(R + SZ + SZ / 2);  // bf16 [Mp][256]
  unsigned short* attbf = (unsigned short*)(R + 2 * SZ);       // bf16 [Mp][256]
  unsigned short* ffbf  = (unsigned short*)R;                  // bf16 [Mp][1024]
  unsigned short* qbf   = (unsigned short*)(ws + 3 * SZ + SZ / 2); // bf16 [Mp][256]
  unsigned short* xbf   = qbf + SZ;                                // bf16 [Mp][256]
  unsigned short* wts   = (unsigned short*)(ws + 4 * SZ + SZ / 2);
  unsigned short* qwT  = wts;                    // [NL][384][256]
  unsigned short* valT = qwT + kNL * 384 * 256;  // [NL][256][256]
  unsigned short* outT = valT + kNL * 256 * 256;
  unsigned short* ff1T = outT + kNL * 256 * 256; // [NL][1024][256]
  unsigned short* ff2T = ff1T + kNL * 1024 * 256;// [NL][256][1024]
  float* qbias = (float*)(ff2T + kNL * 256 * 1024); // [NL][384]

  // --- weight prep ---
  wconv_k<<<dim3(256 / 32, 256 / 32, kNL), 256, 0, stream>>>(off_w, qwT, 256, 256, 0, 384);
  wconv_k<<<dim3(128 / 32, 256 / 32, kNL), 256, 0, stream>>>(aw_w,  qwT, 256, 128, 256, 384);
  wconv_k<<<dim3(256 / 32, 256 / 32, kNL), 256, 0, stream>>>(val_w, valT, 256, 256, 0, 256);
  wconv_k<<<dim3(256 / 32, 256 / 32, kNL), 256, 0, stream>>>(out_w, outT, 256, 256, 0, 256);
  wconv_k<<<dim3(1024 / 32, 256 / 32, kNL), 256, 0, stream>>>(ff1_w, ff1T, 256, 1024, 0, 1024);
  wconv_k<<<dim3(256 / 32, 1024 / 32, kNL), 256, 0, stream>>>(ff2_w, ff2T, 1024, 256, 0, 256);
  biaspack_k<<<(kNL * 384 + 255) / 256, 256, 0, stream>>>(off_b, aw_b, qbias);

  // --- build x0, pos, bf16 copies ---
  const int sides[4]  = {112, 56, 28, 14};
  const int starts[4] = {0, 12544, 15680, 16464};
  for (int l = 0; l < 4; ++l) {
    int HW = sides[l] * sides[l];
    dim3 g((HW + 31) / 32, kD / 32, kB);
    build_xpos_k<<<g, dim3(32, 8), 0, stream>>>(src[l], pos[l], lemb, xb, posb,
                                                xbf, qbf, HW, starts[l], l);
  }

  const dim3 blk(256);
  for (int i = 0; i < kNL; ++i) {
    // qout = (x+pos) @ [off_w | aw_w] + bias   (N=384)
    hgemm_k<0, 0><<<dim3(3, kMT), blk, 0, stream>>>(
        qbf, qwT + (size_t)i * 384 * 256, qbias + i * 384, qout, 384, 256);
    // val = x @ val_w + val_b  -> bf16
    hgemm_k<0, 1><<<dim3(2, kMT), blk, 0, stream>>>(
        xbf, valT + (size_t)i * 256 * 256, val_b + i * 256, valbf, 256, 256);
    // sampling (+softmax fused)
    msdeform_k<<<kM / 4, blk, 0, stream>>>(valbf, qout, attbf);
    // x = LN1(x + attn @ out_w + out_b)  [fused]
    hgemmln_k<0, 0><<<kMT, 512, 0, stream>>>(
        attbf, outT + (size_t)i * 256 * 256, out_b + i * 256, xb,
        ln1_s + i * kD, ln1_b + i * kD, nullptr, xb, xbf, nullptr, 256);
    // ffmid = relu(x @ ff1_w + ff1_b) -> bf16
    hgemm_k<1, 1><<<dim3(8, kMT), blk, 0, stream>>>(
        xbf, ff1T + (size_t)i * 1024 * 256, ff1_b + i * 1024, ffbf, 1024, 256);
    // x = LN2(x + ffmid @ ff2_w + ff2_b)  [fused; last layer -> d_out]
    if (i < kNL - 1) {
      hgemmln_k<1, 0><<<kMT, 512, 0, stream>>>(
          ffbf, ff2T + (size_t)i * 256 * 1024, ff2_b + i * 256, xb,
          ln2_s + i * kD, ln2_b + i * kD, posb, xb, xbf, qbf, 1024);
    } else {
      hgemmln_k<0, 1><<<kMT, 512, 0, stream>>>(
          ffbf, ff2T + (size_t)i * 256 * 1024, ff2_b + i * 256, xb,
          ln2_s + i * kD, ln2_b + i * kD, nullptr, (float*)d_out, nullptr,
          nullptr, 1024);
    }
  }

  tail_k<<<1, 64, 0, stream>>>((float*)d_out);
}

// Round 5
// 1539.404 us; speedup vs baseline: 4.7093x; 1.1283x over previous
//
#include <hip/hip_runtime.h>

// MSDeformAttn Transformer encoder (Deformable-DETR), MI355X.
// Round 5: BM=64 geometry for the fused-LN GEMMs (grid 522, occupancy fix)
//          and for val/qout GEMMs (hgemm64_k). ff1 stays BM=128.

constexpr int kB  = 2;
constexpr int kD  = 256;
constexpr int kNH = 8;
constexpr int kLV = 4;
constexpr int kNP = 4;
constexpr int kNL = 6;
constexpr int kDFF = 1024;
constexpr int kS  = 16660;                 // 112^2+56^2+28^2+14^2
constexpr int kM  = kB * kS;               // 33320
constexpr int kMp = 33408;                 // 261*128 (padded rows)
constexpr int kMT = kMp / 128;             // 261
constexpr int kMT64 = kMp / 64;            // 522

typedef short bf16x8 __attribute__((ext_vector_type(8)));
typedef float f32x4  __attribute__((ext_vector_type(4)));

__device__ __forceinline__ unsigned short f2bf(float x) {
  union { float f; unsigned int u; } v; v.f = x;
  unsigned int r = v.u + 0x7FFFu + ((v.u >> 16) & 1u);
  return (unsigned short)(r >> 16);
}
__device__ __forceinline__ float bf2f(unsigned short u) {
  union { unsigned int u; float f; } v; v.u = ((unsigned int)u) << 16;
  return v.f;
}

#define GLOAD_LDS16(gp, lp)                                                    \
  __builtin_amdgcn_global_load_lds(                                            \
      (const __attribute__((address_space(1))) void*)(gp),                     \
      (__attribute__((address_space(3))) void*)(lp), 16, 0, 0)

// ---------------------------------------------------------------------------
// Input flatten+transpose; also emits bf16 x and bf16 q=x+pos.
// ---------------------------------------------------------------------------
__global__ __launch_bounds__(256) void build_xpos_k(
    const float* __restrict__ src, const float* __restrict__ pos,
    const float* __restrict__ lemb, float* __restrict__ xout,
    float* __restrict__ posout, unsigned short* __restrict__ xbf,
    unsigned short* __restrict__ qbf, int HW, int s0, int lvl)
{
  __shared__ float ts[32][33];
  __shared__ float tp[32][33];
  const int b  = blockIdx.z;
  const int p0 = blockIdx.x * 32, d0 = blockIdx.y * 32;
  const int tx = threadIdx.x, ty = threadIdx.y;   // (32, 8)
  for (int dd = ty; dd < 32; dd += 8) {
    int p = p0 + tx;
    if (p < HW) {
      size_t idx = ((size_t)b * kD + (d0 + dd)) * (size_t)HW + p;
      ts[dd][tx] = src[idx];
      tp[dd][tx] = pos[idx];
    }
  }
  __syncthreads();
  for (int pp = ty; pp < 32; pp += 8) {
    int p = p0 + pp, d = d0 + tx;
    if (p < HW) {
      size_t o = ((size_t)b * kS + (s0 + p)) * (size_t)kD + d;
      float x = ts[tx][pp];
      float pv = tp[tx][pp] + lemb[lvl * kD + d];
      xout[o] = x;
      posout[o] = pv;
      xbf[o] = f2bf(x);
      qbf[o] = f2bf(x + pv);
    }
  }
}

// ---------------------------------------------------------------------------
// Weight convert+transpose: W fp32 [NL][K][N] -> Wt bf16 [NL][rows][K] at rowoff
// ---------------------------------------------------------------------------
__global__ __launch_bounds__(256) void wconv_k(
    const float* __restrict__ W, unsigned short* __restrict__ Wt,
    int K, int N, int rowoff, int rowstotal)
{
  __shared__ float t[32][33];
  const int l = blockIdx.z;
  const int n0 = blockIdx.x * 32, k0 = blockIdx.y * 32;
  const int tx = threadIdx.x & 31, ty = threadIdx.x >> 5;
  const float* Wl = W + (size_t)l * K * N;
  unsigned short* Wtl = Wt + (size_t)l * rowstotal * K;
  for (int kk = ty; kk < 32; kk += 8)
    t[kk][tx] = Wl[(size_t)(k0 + kk) * N + n0 + tx];
  __syncthreads();
  for (int nn = ty; nn < 32; nn += 8)
    Wtl[(size_t)(rowoff + n0 + nn) * K + k0 + tx] = f2bf(t[tx][nn]);
}

__global__ __launch_bounds__(256) void biaspack_k(
    const float* __restrict__ ob, const float* __restrict__ ab,
    float* __restrict__ qb)
{
  int i = blockIdx.x * 256 + threadIdx.x;
  if (i >= kNL * 384) return;
  int l = i / 384, c = i - l * 384;
  qb[i] = (c < 256) ? ob[l * 256 + c] : ab[l * 128 + (c - 256)];
}

// ---------------------------------------------------------------------------
// bf16 MFMA GEMM, BM=128/BN=128 (ff1): 256 threads, 4 waves 2x2 of 64x64.
// ---------------------------------------------------------------------------
template<int RELU, int OUTBF>
__global__ __launch_bounds__(256) void hgemm_k(
    const unsigned short* __restrict__ A, const unsigned short* __restrict__ Bt,
    const float* __restrict__ bias, void* __restrict__ Cout, int N, int K)
{
  __shared__ unsigned short As[128 * 32];
  __shared__ unsigned short Bs[128 * 32];
  const int tid = threadIdx.x;
  const int bm = blockIdx.y * 128;
  const int bn = blockIdx.x * 128;
  const int lane = tid & 63;
  const int wave = tid >> 6;
  const int wr = (wave >> 1) * 64, wc = (wave & 1) * 64;
  const int l15 = lane & 15, l4 = lane >> 4;

  f32x4 acc[4][4] = {};

  const int c0 = tid, c1 = 256 + tid;
  const int r0 = c0 >> 2, kk0 = (c0 & 3) << 3;
  const int r1 = c1 >> 2, kk1 = (c1 & 3) << 3;
  const unsigned short* A0 = A + (size_t)(bm + r0) * K + kk0;
  const unsigned short* A1 = A + (size_t)(bm + r1) * K + kk1;
  const unsigned short* B0 = Bt + (size_t)(bn + r0) * K + kk0;
  const unsigned short* B1 = Bt + (size_t)(bn + r1) * K + kk1;

  for (int k0 = 0; k0 < K; k0 += 32) {
    GLOAD_LDS16(A0 + k0, (char*)As + c0 * 16);
    GLOAD_LDS16(A1 + k0, (char*)As + c1 * 16);
    GLOAD_LDS16(B0 + k0, (char*)Bs + c0 * 16);
    GLOAD_LDS16(B1 + k0, (char*)Bs + c1 * 16);
    __syncthreads();
    bf16x8 af[4], bfr[4];
#pragma unroll
    for (int m = 0; m < 4; ++m)
      af[m] = *(const bf16x8*)&As[(wr + m * 16 + l15) * 32 + l4 * 8];
#pragma unroll
    for (int n = 0; n < 4; ++n)
      bfr[n] = *(const bf16x8*)&Bs[(wc + n * 16 + l15) * 32 + l4 * 8];
#pragma unroll
    for (int m = 0; m < 4; ++m)
#pragma unroll
      for (int n = 0; n < 4; ++n)
        acc[m][n] = __builtin_amdgcn_mfma_f32_16x16x32_bf16(
            af[m], bfr[n], acc[m][n], 0, 0, 0);
    __syncthreads();
  }

#pragma unroll
  for (int n = 0; n < 4; ++n) {
    const int col = bn + wc + n * 16 + l15;
    const float bv = bias[col];
#pragma unroll
    for (int m = 0; m < 4; ++m) {
#pragma unroll
      for (int j = 0; j < 4; ++j) {
        const int row = bm + wr + m * 16 + l4 * 4 + j;
        float v = acc[m][n][j] + bv;
        if (RELU) v = fmaxf(v, 0.f);
        if (OUTBF)
          ((unsigned short*)Cout)[(size_t)row * N + col] = f2bf(v);
        else
          ((float*)Cout)[(size_t)row * N + col] = v;
      }
    }
  }
}

// ---------------------------------------------------------------------------
// bf16 MFMA GEMM, BM=64/BN=128: 256 threads, 4 waves 2x2 of 32x64 (qout/val).
// ---------------------------------------------------------------------------
template<int OUTBF>
__global__ __launch_bounds__(256) void hgemm64_k(
    const unsigned short* __restrict__ A, const unsigned short* __restrict__ Bt,
    const float* __restrict__ bias, void* __restrict__ Cout, int N, int K)
{
  __shared__ unsigned short As[64 * 32];    // 4 KB
  __shared__ unsigned short Bs[128 * 32];   // 8 KB
  const int tid = threadIdx.x;
  const int bm = blockIdx.y * 64;
  const int bn = blockIdx.x * 128;
  const int lane = tid & 63;
  const int wave = tid >> 6;
  const int wr = (wave >> 1) * 32, wc = (wave & 1) * 64;
  const int l15 = lane & 15, l4 = lane >> 4;

  f32x4 acc[2][4] = {};

  const int ra = tid >> 2, ka = (tid & 3) << 3;          // A: 256 chunks
  const unsigned short* A0 = A + (size_t)(bm + ra) * K + ka;
  const int cb1 = 256 + tid;
  const unsigned short* B0 = Bt + (size_t)(bn + (tid >> 2)) * K + ((tid & 3) << 3);
  const unsigned short* B1 = Bt + (size_t)(bn + (cb1 >> 2)) * K + ((cb1 & 3) << 3);

  for (int k0 = 0; k0 < K; k0 += 32) {
    GLOAD_LDS16(A0 + k0, (char*)As + tid * 16);
    GLOAD_LDS16(B0 + k0, (char*)Bs + tid * 16);
    GLOAD_LDS16(B1 + k0, (char*)Bs + cb1 * 16);
    __syncthreads();
    bf16x8 af[2], bfr[4];
#pragma unroll
    for (int m = 0; m < 2; ++m)
      af[m] = *(const bf16x8*)&As[(wr + m * 16 + l15) * 32 + l4 * 8];
#pragma unroll
    for (int n = 0; n < 4; ++n)
      bfr[n] = *(const bf16x8*)&Bs[(wc + n * 16 + l15) * 32 + l4 * 8];
#pragma unroll
    for (int m = 0; m < 2; ++m)
#pragma unroll
      for (int n = 0; n < 4; ++n)
        acc[m][n] = __builtin_amdgcn_mfma_f32_16x16x32_bf16(
            af[m], bfr[n], acc[m][n], 0, 0, 0);
    __syncthreads();
  }

#pragma unroll
  for (int n = 0; n < 4; ++n) {
    const int col = bn + wc + n * 16 + l15;
    const float bv = bias[col];
#pragma unroll
    for (int m = 0; m < 2; ++m) {
#pragma unroll
      for (int j = 0; j < 4; ++j) {
        const int row = bm + wr + m * 16 + l4 * 4 + j;
        float v = acc[m][n][j] + bv;
        if (OUTBF)
          ((unsigned short*)Cout)[(size_t)row * N + col] = f2bf(v);
        else
          ((float*)Cout)[(size_t)row * N + col] = v;
      }
    }
  }
}

// ---------------------------------------------------------------------------
// bf16 MFMA GEMM with fused bias+residual+LayerNorm epilogue.
// BM=64, BN=256 (= full row), BK=32, 512 threads (8 waves, 2x4 of 32x64).
// OUTDST=0: write y->xb fp32 + xbf bf16 (+qbf=y+pos if WQ). OUTDST=1: y->dout.
// ---------------------------------------------------------------------------
template<int WQ, int OUTDST>
__global__ __launch_bounds__(512) void hgemmln_k(
    const unsigned short* __restrict__ A, const unsigned short* __restrict__ Bt,
    const float* __restrict__ bias, const float* __restrict__ Rsd,
    const float* __restrict__ g, const float* __restrict__ beta,
    const float* __restrict__ posb, float* __restrict__ yout,
    unsigned short* __restrict__ xbf, unsigned short* __restrict__ qbf, int K)
{
  __shared__ unsigned short As[64 * 32];    // 4 KB
  __shared__ unsigned short Bs[256 * 32];   // 16 KB
  __shared__ float ssum[64][5];
  __shared__ float ssq[64][5];
  const int tid = threadIdx.x;
  const int bm = blockIdx.x * 64;
  const int lane = tid & 63;
  const int wave = tid >> 6;
  const int wr = (wave >> 2) * 32, wc = (wave & 3) * 64;
  const int l15 = lane & 15, l4 = lane >> 4;

  f32x4 acc[2][4] = {};

  const unsigned short* A0 = A + (size_t)(bm + (tid >> 2)) * K + ((tid & 3) << 3);
  const int cb1 = 512 + tid;
  const unsigned short* B0 = Bt + (size_t)(tid >> 2) * K + ((tid & 3) << 3);
  const unsigned short* B1 = Bt + (size_t)(cb1 >> 2) * K + ((cb1 & 3) << 3);

  for (int k0 = 0; k0 < K; k0 += 32) {
    if (tid < 256) GLOAD_LDS16(A0 + k0, (char*)As + tid * 16);
    GLOAD_LDS16(B0 + k0, (char*)Bs + tid * 16);
    GLOAD_LDS16(B1 + k0, (char*)Bs + cb1 * 16);
    __syncthreads();
    bf16x8 af[2], bfr[4];
#pragma unroll
    for (int m = 0; m < 2; ++m)
      af[m] = *(const bf16x8*)&As[(wr + m * 16 + l15) * 32 + l4 * 8];
#pragma unroll
    for (int n = 0; n < 4; ++n)
      bfr[n] = *(const bf16x8*)&Bs[(wc + n * 16 + l15) * 32 + l4 * 8];
#pragma unroll
    for (int m = 0; m < 2; ++m)
#pragma unroll
      for (int n = 0; n < 4; ++n)
        acc[m][n] = __builtin_amdgcn_mfma_f32_16x16x32_bf16(
            af[m], bfr[n], acc[m][n], 0, 0, 0);
    __syncthreads();
  }

  // epilogue: v = acc + bias + residual (in regs)
  float bv[4], gv[4], btv[4];
#pragma unroll
  for (int n = 0; n < 4; ++n) {
    const int col = wc + n * 16 + l15;
    bv[n] = bias[col];
    gv[n] = g[col];
    btv[n] = beta[col];
  }
#pragma unroll
  for (int m = 0; m < 2; ++m) {
#pragma unroll
    for (int j = 0; j < 4; ++j) {
      const int row = bm + wr + m * 16 + l4 * 4 + j;
#pragma unroll
      for (int n = 0; n < 4; ++n)
        acc[m][n][j] += bv[n] + Rsd[(size_t)row * kD + wc + n * 16 + l15];
    }
  }
  // per-row partial sums over this wave's 64 cols, reduce over 16-lane group
#pragma unroll
  for (int m = 0; m < 2; ++m) {
#pragma unroll
    for (int j = 0; j < 4; ++j) {
      float s = acc[m][0][j] + acc[m][1][j] + acc[m][2][j] + acc[m][3][j];
      float q = acc[m][0][j] * acc[m][0][j] + acc[m][1][j] * acc[m][1][j] +
                acc[m][2][j] * acc[m][2][j] + acc[m][3][j] * acc[m][3][j];
#pragma unroll
      for (int d2 = 1; d2 < 16; d2 <<= 1) {
        s += __shfl_xor(s, d2, 64);
        q += __shfl_xor(q, d2, 64);
      }
      if (l15 == 0) {
        const int r = wr + m * 16 + l4 * 4 + j;
        ssum[r][wave & 3] = s;
        ssq[r][wave & 3] = q;
      }
    }
  }
  __syncthreads();
#pragma unroll
  for (int m = 0; m < 2; ++m) {
#pragma unroll
    for (int j = 0; j < 4; ++j) {
      const int r = wr + m * 16 + l4 * 4 + j;
      const int row = bm + r;
      const float mean = (ssum[r][0] + ssum[r][1] + ssum[r][2] + ssum[r][3]) *
                         (1.0f / kD);
      const float var = (ssq[r][0] + ssq[r][1] + ssq[r][2] + ssq[r][3]) *
                        (1.0f / kD) - mean * mean;
      const float rstd = rsqrtf(var + 1e-5f);
      if (row < kM) {
#pragma unroll
        for (int n = 0; n < 4; ++n) {
          const int col = wc + n * 16 + l15;
          const float y = (acc[m][n][j] - mean) * rstd * gv[n] + btv[n];
          const size_t o = (size_t)row * kD + col;
          if (OUTDST) {
            yout[o] = y;
          } else {
            yout[o] = y;
            xbf[o] = f2bf(y);
            if (WQ) qbf[o] = f2bf(y + posb[o]);
          }
        }
      }
    }
  }
}

// ---------------------------------------------------------------------------
// MS deformable attention sampling (+fused softmax), 4 queries per block.
// ---------------------------------------------------------------------------
__global__ __launch_bounds__(256) void msdeform_k(
    const unsigned short* __restrict__ val, const float* __restrict__ qout,
    unsigned short* __restrict__ outbf)
{
  __shared__ int   sIdx[4][4][128];   // [corner][q][sp*8+h]
  __shared__ float sW[4][4][128];
  const int bs0 = blockIdx.x * 4;
  const int tid = threadIdx.x;

#pragma unroll
  for (int it = 0; it < 2; ++it) {
    const int item = tid + it * 256;
    const int q = item >> 7;         // 0..3
    const int t = item & 127;        // h*16 + l*4 + p
    const int bs = bs0 + q;
    const int b = bs / kS, s = bs - b * kS;
    const int l = (t & 15) >> 2;

    const float logit = qout[(size_t)bs * 384 + 256 + t];
    float mx = logit;
#pragma unroll
    for (int d2 = 1; d2 < 16; d2 <<= 1) mx = fmaxf(mx, __shfl_xor(mx, d2, 64));
    float e = __expf(logit - mx);
    float sm = e;
#pragma unroll
    for (int d2 = 1; d2 < 16; d2 <<= 1) sm += __shfl_xor(sm, d2, 64);
    const float a = e / sm;

    int ls, sideq;
    if (s < 12544)      { ls = s;         sideq = 112; }
    else if (s < 15680) { ls = s - 12544; sideq = 56;  }
    else if (s < 16464) { ls = s - 15680; sideq = 28;  }
    else                { ls = s - 16464; sideq = 14;  }
    const float rx = ((ls % sideq) + 0.5f) / (float)sideq;
    const float ry = ((ls / sideq) + 0.5f) / (float)sideq;

    const int side  = 112 >> l;
    const int start = (l >= 1 ? 12544 : 0) + (l >= 2 ? 3136 : 0) + (l >= 3 ? 784 : 0);
    const float ox = qout[(size_t)bs * 384 + t * 2 + 0];
    const float oy = qout[(size_t)bs * 384 + t * 2 + 1];
    const float xx = rx * side + ox - 0.5f;
    const float yy = ry * side + oy - 0.5f;
    const float xf = floorf(xx), yf = floorf(yy);
    const float lx = xx - xf, ly = yy - yf;
    const int x0 = (int)xf, y0 = (int)yf;
    const float w00 = (1.f - lx) * (1.f - ly) * a, w10 = lx * (1.f - ly) * a;
    const float w01 = (1.f - lx) * ly * a,         w11 = lx * ly * a;
    const bool xv0 = (unsigned)x0 < (unsigned)side, xv1 = (unsigned)(x0 + 1) < (unsigned)side;
    const bool yv0 = (unsigned)y0 < (unsigned)side, yv1 = (unsigned)(y0 + 1) < (unsigned)side;
    const int cx0 = min(max(x0, 0), side - 1), cx1 = min(max(x0 + 1, 0), side - 1);
    const int cy0 = min(max(y0, 0), side - 1), cy1 = min(max(y0 + 1, 0), side - 1);
    const int rowbase = b * kS + start;
    const int t2 = (t & 15) * 8 + (t >> 4);   // sp*8 + h
    sIdx[0][q][t2] = rowbase + cy0 * side + cx0;
    sIdx[1][q][t2] = rowbase + cy0 * side + cx1;
    sIdx[2][q][t2] = rowbase + cy1 * side + cx0;
    sIdx[3][q][t2] = rowbase + cy1 * side + cx1;
    sW[0][q][t2] = (xv0 && yv0) ? w00 : 0.f;
    sW[1][q][t2] = (xv1 && yv0) ? w10 : 0.f;
    sW[2][q][t2] = (xv0 && yv1) ? w01 : 0.f;
    sW[3][q][t2] = (xv1 && yv1) ? w11 : 0.f;
  }
  __syncthreads();

  const int q  = tid >> 6;          // wave = query
  const int h  = (tid >> 3) & 7;
  const int l8 = tid & 7;
  const unsigned short* vb = val + h * 32 + l8 * 4;

  float a0 = 0.f, a1 = 0.f, a2 = 0.f, a3 = 0.f;
#pragma unroll
  for (int sp = 0; sp < 16; ++sp) {
    const int t2 = sp * 8 + h;
#pragma unroll
    for (int c = 0; c < 4; ++c) {
      const int r = sIdx[c][q][t2];
      const float w = sW[c][q][t2];
      const ushort4 v4 = *(const ushort4*)(vb + (size_t)r * 256);
      a0 = fmaf(w, bf2f(v4.x), a0);
      a1 = fmaf(w, bf2f(v4.y), a1);
      a2 = fmaf(w, bf2f(v4.z), a2);
      a3 = fmaf(w, bf2f(v4.w), a3);
    }
  }
  ushort4 o;
  o.x = f2bf(a0); o.y = f2bf(a1); o.z = f2bf(a2); o.w = f2bf(a3);
  *(ushort4*)(outbf + (size_t)(bs0 + q) * 256 + h * 32 + l8 * 4) = o;
}

// ---------------------------------------------------------------------------
__global__ void tail_k(float* __restrict__ out)
{
  if (threadIdx.x == 0) {
    const size_t n = (size_t)kM * kD;
    out[n + 0] = 112.f; out[n + 1] = 112.f;
    out[n + 2] = 56.f;  out[n + 3] = 56.f;
    out[n + 4] = 28.f;  out[n + 5] = 28.f;
    out[n + 6] = 14.f;  out[n + 7] = 14.f;
    out[n + 8] = 0.f;   out[n + 9] = 12544.f;
    out[n + 10] = 15680.f; out[n + 11] = 16464.f;
  }
}

// ---------------------------------------------------------------------------
extern "C" void kernel_launch(void* const* d_in, const int* in_sizes, int n_in,
                              void* d_out, int out_size, void* d_ws, size_t ws_size,
                              hipStream_t stream)
{
  const float* src[4] = {(const float*)d_in[0], (const float*)d_in[2],
                         (const float*)d_in[4], (const float*)d_in[6]};
  const float* pos[4] = {(const float*)d_in[1], (const float*)d_in[3],
                         (const float*)d_in[5], (const float*)d_in[7]};
  const float* lemb  = (const float*)d_in[8];
  const float* off_w = (const float*)d_in[9];
  const float* off_b = (const float*)d_in[10];
  const float* aw_w  = (const float*)d_in[11];
  const float* aw_b  = (const float*)d_in[12];
  const float* val_w = (const float*)d_in[13];
  const float* val_b = (const float*)d_in[14];
  const float* out_w = (const float*)d_in[15];
  const float* out_b = (const float*)d_in[16];
  const float* ln1_s = (const float*)d_in[17];
  const float* ln1_b = (const float*)d_in[18];
  const float* ff1_w = (const float*)d_in[19];
  const float* ff1_b = (const float*)d_in[20];
  const float* ff2_w = (const float*)d_in[21];
  const float* ff2_b = (const float*)d_in[22];
  const float* ln2_s = (const float*)d_in[23];
  const float* ln2_b = (const float*)d_in[24];

  const size_t SZ = (size_t)kMp * kD;      // 8,552,448 floats
  float* ws   = (float*)d_ws;
  float* posb = (float*)d_out;             // pos lives in d_out until last layer
  float* xb   = ws;                        // fp32 [SZ]
  float* R    = ws + SZ;                   // reusable region
  float* qout = R;                         // fp32 [Mp][384] = 1.5*SZ
  unsigned short* valbf = (unsigned short*)(R + SZ + SZ / 2);  // bf16 [Mp][256]
  unsigned short* attbf = (unsigned short*)(R + 2 * SZ);       // bf16 [Mp][256]
  unsigned short* ffbf  = (unsigned short*)R;                  // bf16 [Mp][1024]
  unsigned short* qbf   = (unsigned short*)(ws + 3 * SZ + SZ / 2); // bf16 [Mp][256]
  unsigned short* xbf   = qbf + SZ;                                // bf16 [Mp][256]
  unsigned short* wts   = (unsigned short*)(ws + 4 * SZ + SZ / 2);
  unsigned short* qwT  = wts;                    // [NL][384][256]
  unsigned short* valT = qwT + kNL * 384 * 256;  // [NL][256][256]
  unsigned short* outT = valT + kNL * 256 * 256;
  unsigned short* ff1T = outT + kNL * 256 * 256; // [NL][1024][256]
  unsigned short* ff2T = ff1T + kNL * 1024 * 256;// [NL][256][1024]
  float* qbias = (float*)(ff2T + kNL * 256 * 1024); // [NL][384]

  // --- weight prep ---
  wconv_k<<<dim3(256 / 32, 256 / 32, kNL), 256, 0, stream>>>(off_w, qwT, 256, 256, 0, 384);
  wconv_k<<<dim3(128 / 32, 256 / 32, kNL), 256, 0, stream>>>(aw_w,  qwT, 256, 128, 256, 384);
  wconv_k<<<dim3(256 / 32, 256 / 32, kNL), 256, 0, stream>>>(val_w, valT, 256, 256, 0, 256);
  wconv_k<<<dim3(256 / 32, 256 / 32, kNL), 256, 0, stream>>>(out_w, outT, 256, 256, 0, 256);
  wconv_k<<<dim3(1024 / 32, 256 / 32, kNL), 256, 0, stream>>>(ff1_w, ff1T, 256, 1024, 0, 1024);
  wconv_k<<<dim3(256 / 32, 1024 / 32, kNL), 256, 0, stream>>>(ff2_w, ff2T, 1024, 256, 0, 256);
  biaspack_k<<<(kNL * 384 + 255) / 256, 256, 0, stream>>>(off_b, aw_b, qbias);

  // --- build x0, pos, bf16 copies ---
  const int sides[4]  = {112, 56, 28, 14};
  const int starts[4] = {0, 12544, 15680, 16464};
  for (int l = 0; l < 4; ++l) {
    int HW = sides[l] * sides[l];
    dim3 g((HW + 31) / 32, kD / 32, kB);
    build_xpos_k<<<g, dim3(32, 8), 0, stream>>>(src[l], pos[l], lemb, xb, posb,
                                                xbf, qbf, HW, starts[l], l);
  }

  const dim3 blk(256);
  for (int i = 0; i < kNL; ++i) {
    // qout = (x+pos) @ [off_w | aw_w] + bias   (N=384)
    hgemm64_k<0><<<dim3(3, kMT64), blk, 0, stream>>>(
        qbf, qwT + (size_t)i * 384 * 256, qbias + i * 384, qout, 384, 256);
    // val = x @ val_w + val_b  -> bf16
    hgemm64_k<1><<<dim3(2, kMT64), blk, 0, stream>>>(
        xbf, valT + (size_t)i * 256 * 256, val_b + i * 256, valbf, 256, 256);
    // sampling (+softmax fused)
    msdeform_k<<<kM / 4, blk, 0, stream>>>(valbf, qout, attbf);
    // x = LN1(x + attn @ out_w + out_b)  [fused]
    hgemmln_k<0, 0><<<kMT64, 512, 0, stream>>>(
        attbf, outT + (size_t)i * 256 * 256, out_b + i * 256, xb,
        ln1_s + i * kD, ln1_b + i * kD, nullptr, xb, xbf, nullptr, 256);
    // ffmid = relu(x @ ff1_w + ff1_b) -> bf16
    hgemm_k<1, 1><<<dim3(8, kMT), blk, 0, stream>>>(
        xbf, ff1T + (size_t)i * 1024 * 256, ff1_b + i * 1024, ffbf, 1024, 256);
    // x = LN2(x + ffmid @ ff2_w + ff2_b)  [fused; last layer -> d_out]
    if (i < kNL - 1) {
      hgemmln_k<1, 0><<<kMT64, 512, 0, stream>>>(
          ffbf, ff2T + (size_t)i * 256 * 1024, ff2_b + i * 256, xb,
          ln2_s + i * kD, ln2_b + i * kD, posb, xb, xbf, qbf, 1024);
    } else {
      hgemmln_k<0, 1><<<kMT64, 512, 0, stream>>>(
          ffbf, ff2T + (size_t)i * 256 * 1024, ff2_b + i * 256, xb,
          ln2_s + i * kD, ln2_b + i * kD, nullptr, (float*)d_out, nullptr,
          nullptr, 1024);
    }
  }

  tail_k<<<1, 64, 0, stream>>>((float*)d_out);
}

// Round 6
// 1510.230 us; speedup vs baseline: 4.8003x; 1.0193x over previous
//
#include <hip/hip_runtime.h>

// MSDeformAttn Transformer encoder (Deformable-DETR), MI355X.
// Round 6: hgemmln_k BM=32 (grid 1044) + 2-phase double-buffered prefetch;
//          hgemm64_k gets the same dbuf prefetch. ff1/msdeform unchanged.

constexpr int kB  = 2;
constexpr int kD  = 256;
constexpr int kNH = 8;
constexpr int kLV = 4;
constexpr int kNP = 4;
constexpr int kNL = 6;
constexpr int kDFF = 1024;
constexpr int kS  = 16660;                 // 112^2+56^2+28^2+14^2
constexpr int kM  = kB * kS;               // 33320
constexpr int kMp = 33408;                 // 261*128 (padded rows)
constexpr int kMT = kMp / 128;             // 261
constexpr int kMT64 = kMp / 64;            // 522
constexpr int kMT32 = kMp / 32;            // 1044

typedef short bf16x8 __attribute__((ext_vector_type(8)));
typedef float f32x4  __attribute__((ext_vector_type(4)));

__device__ __forceinline__ unsigned short f2bf(float x) {
  union { float f; unsigned int u; } v; v.f = x;
  unsigned int r = v.u + 0x7FFFu + ((v.u >> 16) & 1u);
  return (unsigned short)(r >> 16);
}
__device__ __forceinline__ float bf2f(unsigned short u) {
  union { unsigned int u; float f; } v; v.u = ((unsigned int)u) << 16;
  return v.f;
}

#define GLOAD_LDS16(gp, lp)                                                    \
  __builtin_amdgcn_global_load_lds(                                            \
      (const __attribute__((address_space(1))) void*)(gp),                     \
      (__attribute__((address_space(3))) void*)(lp), 16, 0, 0)

// ---------------------------------------------------------------------------
// Input flatten+transpose; also emits bf16 x and bf16 q=x+pos.
// ---------------------------------------------------------------------------
__global__ __launch_bounds__(256) void build_xpos_k(
    const float* __restrict__ src, const float* __restrict__ pos,
    const float* __restrict__ lemb, float* __restrict__ xout,
    float* __restrict__ posout, unsigned short* __restrict__ xbf,
    unsigned short* __restrict__ qbf, int HW, int s0, int lvl)
{
  __shared__ float ts[32][33];
  __shared__ float tp[32][33];
  const int b  = blockIdx.z;
  const int p0 = blockIdx.x * 32, d0 = blockIdx.y * 32;
  const int tx = threadIdx.x, ty = threadIdx.y;   // (32, 8)
  for (int dd = ty; dd < 32; dd += 8) {
    int p = p0 + tx;
    if (p < HW) {
      size_t idx = ((size_t)b * kD + (d0 + dd)) * (size_t)HW + p;
      ts[dd][tx] = src[idx];
      tp[dd][tx] = pos[idx];
    }
  }
  __syncthreads();
  for (int pp = ty; pp < 32; pp += 8) {
    int p = p0 + pp, d = d0 + tx;
    if (p < HW) {
      size_t o = ((size_t)b * kS + (s0 + p)) * (size_t)kD + d;
      float x = ts[tx][pp];
      float pv = tp[tx][pp] + lemb[lvl * kD + d];
      xout[o] = x;
      posout[o] = pv;
      xbf[o] = f2bf(x);
      qbf[o] = f2bf(x + pv);
    }
  }
}

// ---------------------------------------------------------------------------
// Weight convert+transpose: W fp32 [NL][K][N] -> Wt bf16 [NL][rows][K] at rowoff
// ---------------------------------------------------------------------------
__global__ __launch_bounds__(256) void wconv_k(
    const float* __restrict__ W, unsigned short* __restrict__ Wt,
    int K, int N, int rowoff, int rowstotal)
{
  __shared__ float t[32][33];
  const int l = blockIdx.z;
  const int n0 = blockIdx.x * 32, k0 = blockIdx.y * 32;
  const int tx = threadIdx.x & 31, ty = threadIdx.x >> 5;
  const float* Wl = W + (size_t)l * K * N;
  unsigned short* Wtl = Wt + (size_t)l * rowstotal * K;
  for (int kk = ty; kk < 32; kk += 8)
    t[kk][tx] = Wl[(size_t)(k0 + kk) * N + n0 + tx];
  __syncthreads();
  for (int nn = ty; nn < 32; nn += 8)
    Wtl[(size_t)(rowoff + n0 + nn) * K + k0 + tx] = f2bf(t[tx][nn]);
}

__global__ __launch_bounds__(256) void biaspack_k(
    const float* __restrict__ ob, const float* __restrict__ ab,
    float* __restrict__ qb)
{
  int i = blockIdx.x * 256 + threadIdx.x;
  if (i >= kNL * 384) return;
  int l = i / 384, c = i - l * 384;
  qb[i] = (c < 256) ? ob[l * 256 + c] : ab[l * 128 + (c - 256)];
}

// ---------------------------------------------------------------------------
// bf16 MFMA GEMM, BM=128/BN=128 (ff1): 256 threads, 4 waves 2x2 of 64x64.
// ---------------------------------------------------------------------------
template<int RELU, int OUTBF>
__global__ __launch_bounds__(256) void hgemm_k(
    const unsigned short* __restrict__ A, const unsigned short* __restrict__ Bt,
    const float* __restrict__ bias, void* __restrict__ Cout, int N, int K)
{
  __shared__ unsigned short As[128 * 32];
  __shared__ unsigned short Bs[128 * 32];
  const int tid = threadIdx.x;
  const int bm = blockIdx.y * 128;
  const int bn = blockIdx.x * 128;
  const int lane = tid & 63;
  const int wave = tid >> 6;
  const int wr = (wave >> 1) * 64, wc = (wave & 1) * 64;
  const int l15 = lane & 15, l4 = lane >> 4;

  f32x4 acc[4][4] = {};

  const int c0 = tid, c1 = 256 + tid;
  const int r0 = c0 >> 2, kk0 = (c0 & 3) << 3;
  const int r1 = c1 >> 2, kk1 = (c1 & 3) << 3;
  const unsigned short* A0 = A + (size_t)(bm + r0) * K + kk0;
  const unsigned short* A1 = A + (size_t)(bm + r1) * K + kk1;
  const unsigned short* B0 = Bt + (size_t)(bn + r0) * K + kk0;
  const unsigned short* B1 = Bt + (size_t)(bn + r1) * K + kk1;

  for (int k0 = 0; k0 < K; k0 += 32) {
    GLOAD_LDS16(A0 + k0, (char*)As + c0 * 16);
    GLOAD_LDS16(A1 + k0, (char*)As + c1 * 16);
    GLOAD_LDS16(B0 + k0, (char*)Bs + c0 * 16);
    GLOAD_LDS16(B1 + k0, (char*)Bs + c1 * 16);
    __syncthreads();
    bf16x8 af[4], bfr[4];
#pragma unroll
    for (int m = 0; m < 4; ++m)
      af[m] = *(const bf16x8*)&As[(wr + m * 16 + l15) * 32 + l4 * 8];
#pragma unroll
    for (int n = 0; n < 4; ++n)
      bfr[n] = *(const bf16x8*)&Bs[(wc + n * 16 + l15) * 32 + l4 * 8];
#pragma unroll
    for (int m = 0; m < 4; ++m)
#pragma unroll
      for (int n = 0; n < 4; ++n)
        acc[m][n] = __builtin_amdgcn_mfma_f32_16x16x32_bf16(
            af[m], bfr[n], acc[m][n], 0, 0, 0);
    __syncthreads();
  }

#pragma unroll
  for (int n = 0; n < 4; ++n) {
    const int col = bn + wc + n * 16 + l15;
    const float bv = bias[col];
#pragma unroll
    for (int m = 0; m < 4; ++m) {
#pragma unroll
      for (int j = 0; j < 4; ++j) {
        const int row = bm + wr + m * 16 + l4 * 4 + j;
        float v = acc[m][n][j] + bv;
        if (RELU) v = fmaxf(v, 0.f);
        if (OUTBF)
          ((unsigned short*)Cout)[(size_t)row * N + col] = f2bf(v);
        else
          ((float*)Cout)[(size_t)row * N + col] = v;
      }
    }
  }
}

// ---------------------------------------------------------------------------
// bf16 MFMA GEMM, BM=64/BN=128: 256 threads, 4 waves 2x2 of 32x64 (qout/val),
// double-buffered 2-phase prefetch.
// ---------------------------------------------------------------------------
template<int OUTBF>
__global__ __launch_bounds__(256) void hgemm64_k(
    const unsigned short* __restrict__ A, const unsigned short* __restrict__ Bt,
    const float* __restrict__ bias, void* __restrict__ Cout, int N, int K)
{
  __shared__ unsigned short As[2][64 * 32];    // 2x4 KB
  __shared__ unsigned short Bs[2][128 * 32];   // 2x8 KB
  const int tid = threadIdx.x;
  const int bm = blockIdx.y * 64;
  const int bn = blockIdx.x * 128;
  const int lane = tid & 63;
  const int wave = tid >> 6;
  const int wr = (wave >> 1) * 32, wc = (wave & 1) * 64;
  const int l15 = lane & 15, l4 = lane >> 4;

  f32x4 acc[2][4] = {};

  const unsigned short* A0 = A + (size_t)(bm + (tid >> 2)) * K + ((tid & 3) << 3);
  const int cb1 = 256 + tid;
  const unsigned short* B0 = Bt + (size_t)(bn + (tid >> 2)) * K + ((tid & 3) << 3);
  const unsigned short* B1 = Bt + (size_t)(bn + (cb1 >> 2)) * K + ((cb1 & 3) << 3);

#define STAGE64(buf, k0)                                                       \
  do {                                                                         \
    GLOAD_LDS16(A0 + (k0), (char*)As[buf] + tid * 16);                         \
    GLOAD_LDS16(B0 + (k0), (char*)Bs[buf] + tid * 16);                         \
    GLOAD_LDS16(B1 + (k0), (char*)Bs[buf] + cb1 * 16);                         \
  } while (0)

  STAGE64(0, 0);
  __syncthreads();
  int cur = 0;
  for (int k0 = 0; k0 < K; k0 += 32) {
    if (k0 + 32 < K) STAGE64(cur ^ 1, k0 + 32);
    bf16x8 af[2], bfr[4];
#pragma unroll
    for (int m = 0; m < 2; ++m)
      af[m] = *(const bf16x8*)&As[cur][(wr + m * 16 + l15) * 32 + l4 * 8];
#pragma unroll
    for (int n = 0; n < 4; ++n)
      bfr[n] = *(const bf16x8*)&Bs[cur][(wc + n * 16 + l15) * 32 + l4 * 8];
#pragma unroll
    for (int m = 0; m < 2; ++m)
#pragma unroll
      for (int n = 0; n < 4; ++n)
        acc[m][n] = __builtin_amdgcn_mfma_f32_16x16x32_bf16(
            af[m], bfr[n], acc[m][n], 0, 0, 0);
    __syncthreads();
    cur ^= 1;
  }
#undef STAGE64

#pragma unroll
  for (int n = 0; n < 4; ++n) {
    const int col = bn + wc + n * 16 + l15;
    const float bv = bias[col];
#pragma unroll
    for (int m = 0; m < 2; ++m) {
#pragma unroll
      for (int j = 0; j < 4; ++j) {
        const int row = bm + wr + m * 16 + l4 * 4 + j;
        float v = acc[m][n][j] + bv;
        if (OUTBF)
          ((unsigned short*)Cout)[(size_t)row * N + col] = f2bf(v);
        else
          ((float*)Cout)[(size_t)row * N + col] = v;
      }
    }
  }
}

// ---------------------------------------------------------------------------
// bf16 MFMA GEMM with fused bias+residual+LayerNorm epilogue.
// BM=32, BN=256 (= full row), BK=32, 256 threads (4 waves of 32x64),
// double-buffered 2-phase prefetch. Grid = kMp/32 = 1044.
// OUTDST=0: write y->xb fp32 + xbf bf16 (+qbf=y+pos if WQ). OUTDST=1: y->dout.
// ---------------------------------------------------------------------------
template<int WQ, int OUTDST>
__global__ __launch_bounds__(256) void hgemmln_k(
    const unsigned short* __restrict__ A, const unsigned short* __restrict__ Bt,
    const float* __restrict__ bias, const float* __restrict__ Rsd,
    const float* __restrict__ g, const float* __restrict__ beta,
    const float* __restrict__ posb, float* __restrict__ yout,
    unsigned short* __restrict__ xbf, unsigned short* __restrict__ qbf, int K)
{
  __shared__ unsigned short As[2][32 * 32];    // 2x2 KB
  __shared__ unsigned short Bs[2][256 * 32];   // 2x16 KB
  __shared__ float ssum[32][5];
  __shared__ float ssq[32][5];
  const int tid = threadIdx.x;
  const int bm = blockIdx.x * 32;
  const int lane = tid & 63;
  const int wave = tid >> 6;          // 0..3
  const int wc = wave * 64;
  const int l15 = lane & 15, l4 = lane >> 4;

  f32x4 acc[2][4] = {};

  // A: 128 chunks (threads 0..127): row=tid>>2, koff=(tid&3)*8
  const unsigned short* Aq = A + (size_t)(bm + (tid >> 2)) * K + ((tid & 3) << 3);
  // B: 1024 chunks in 4 passes: pass p, chunk=p*256+tid -> row=p*64+(tid>>2)
  const unsigned short* Bq0 = Bt + (size_t)(0 * 64 + (tid >> 2)) * K + ((tid & 3) << 3);
  const unsigned short* Bq1 = Bt + (size_t)(1 * 64 + (tid >> 2)) * K + ((tid & 3) << 3);
  const unsigned short* Bq2 = Bt + (size_t)(2 * 64 + (tid >> 2)) * K + ((tid & 3) << 3);
  const unsigned short* Bq3 = Bt + (size_t)(3 * 64 + (tid >> 2)) * K + ((tid & 3) << 3);

#define STAGE_LN(buf, k0)                                                      \
  do {                                                                         \
    if (tid < 128) GLOAD_LDS16(Aq + (k0), (char*)As[buf] + tid * 16);          \
    GLOAD_LDS16(Bq0 + (k0), (char*)Bs[buf] + (0 * 256 + tid) * 16);            \
    GLOAD_LDS16(Bq1 + (k0), (char*)Bs[buf] + (1 * 256 + tid) * 16);            \
    GLOAD_LDS16(Bq2 + (k0), (char*)Bs[buf] + (2 * 256 + tid) * 16);            \
    GLOAD_LDS16(Bq3 + (k0), (char*)Bs[buf] + (3 * 256 + tid) * 16);            \
  } while (0)

  STAGE_LN(0, 0);
  __syncthreads();
  int cur = 0;
  for (int k0 = 0; k0 < K; k0 += 32) {
    if (k0 + 32 < K) STAGE_LN(cur ^ 1, k0 + 32);
    bf16x8 af[2], bfr[4];
#pragma unroll
    for (int m = 0; m < 2; ++m)
      af[m] = *(const bf16x8*)&As[cur][(m * 16 + l15) * 32 + l4 * 8];
#pragma unroll
    for (int n = 0; n < 4; ++n)
      bfr[n] = *(const bf16x8*)&Bs[cur][(wc + n * 16 + l15) * 32 + l4 * 8];
#pragma unroll
    for (int m = 0; m < 2; ++m)
#pragma unroll
      for (int n = 0; n < 4; ++n)
        acc[m][n] = __builtin_amdgcn_mfma_f32_16x16x32_bf16(
            af[m], bfr[n], acc[m][n], 0, 0, 0);
    __syncthreads();
    cur ^= 1;
  }
#undef STAGE_LN

  // epilogue: v = acc + bias + residual (in regs)
  float bv[4], gv[4], btv[4];
#pragma unroll
  for (int n = 0; n < 4; ++n) {
    const int col = wc + n * 16 + l15;
    bv[n] = bias[col];
    gv[n] = g[col];
    btv[n] = beta[col];
  }
#pragma unroll
  for (int m = 0; m < 2; ++m) {
#pragma unroll
    for (int j = 0; j < 4; ++j) {
      const int row = bm + m * 16 + l4 * 4 + j;
#pragma unroll
      for (int n = 0; n < 4; ++n)
        acc[m][n][j] += bv[n] + Rsd[(size_t)row * kD + wc + n * 16 + l15];
    }
  }
  // per-row partial sums over this wave's 64 cols, reduce over 16-lane group
#pragma unroll
  for (int m = 0; m < 2; ++m) {
#pragma unroll
    for (int j = 0; j < 4; ++j) {
      float s = acc[m][0][j] + acc[m][1][j] + acc[m][2][j] + acc[m][3][j];
      float q = acc[m][0][j] * acc[m][0][j] + acc[m][1][j] * acc[m][1][j] +
                acc[m][2][j] * acc[m][2][j] + acc[m][3][j] * acc[m][3][j];
#pragma unroll
      for (int d2 = 1; d2 < 16; d2 <<= 1) {
        s += __shfl_xor(s, d2, 64);
        q += __shfl_xor(q, d2, 64);
      }
      if (l15 == 0) {
        const int r = m * 16 + l4 * 4 + j;
        ssum[r][wave] = s;
        ssq[r][wave] = q;
      }
    }
  }
  __syncthreads();
#pragma unroll
  for (int m = 0; m < 2; ++m) {
#pragma unroll
    for (int j = 0; j < 4; ++j) {
      const int r = m * 16 + l4 * 4 + j;
      const int row = bm + r;
      const float mean = (ssum[r][0] + ssum[r][1] + ssum[r][2] + ssum[r][3]) *
                         (1.0f / kD);
      const float var = (ssq[r][0] + ssq[r][1] + ssq[r][2] + ssq[r][3]) *
                        (1.0f / kD) - mean * mean;
      const float rstd = rsqrtf(var + 1e-5f);
      if (row < kM) {
#pragma unroll
        for (int n = 0; n < 4; ++n) {
          const int col = wc + n * 16 + l15;
          const float y = (acc[m][n][j] - mean) * rstd * gv[n] + btv[n];
          const size_t o = (size_t)row * kD + col;
          if (OUTDST) {
            yout[o] = y;
          } else {
            yout[o] = y;
            xbf[o] = f2bf(y);
            if (WQ) qbf[o] = f2bf(y + posb[o]);
          }
        }
      }
    }
  }
}

// ---------------------------------------------------------------------------
// MS deformable attention sampling (+fused softmax), 4 queries per block.
// ---------------------------------------------------------------------------
__global__ __launch_bounds__(256) void msdeform_k(
    const unsigned short* __restrict__ val, const float* __restrict__ qout,
    unsigned short* __restrict__ outbf)
{
  __shared__ int   sIdx[4][4][128];   // [corner][q][sp*8+h]
  __shared__ float sW[4][4][128];
  const int bs0 = blockIdx.x * 4;
  const int tid = threadIdx.x;

#pragma unroll
  for (int it = 0; it < 2; ++it) {
    const int item = tid + it * 256;
    const int q = item >> 7;         // 0..3
    const int t = item & 127;        // h*16 + l*4 + p
    const int bs = bs0 + q;
    const int b = bs / kS, s = bs - b * kS;
    const int l = (t & 15) >> 2;

    const float logit = qout[(size_t)bs * 384 + 256 + t];
    float mx = logit;
#pragma unroll
    for (int d2 = 1; d2 < 16; d2 <<= 1) mx = fmaxf(mx, __shfl_xor(mx, d2, 64));
    float e = __expf(logit - mx);
    float sm = e;
#pragma unroll
    for (int d2 = 1; d2 < 16; d2 <<= 1) sm += __shfl_xor(sm, d2, 64);
    const float a = e / sm;

    int ls, sideq;
    if (s < 12544)      { ls = s;         sideq = 112; }
    else if (s < 15680) { ls = s - 12544; sideq = 56;  }
    else if (s < 16464) { ls = s - 15680; sideq = 28;  }
    else                { ls = s - 16464; sideq = 14;  }
    const float rx = ((ls % sideq) + 0.5f) / (float)sideq;
    const float ry = ((ls / sideq) + 0.5f) / (float)sideq;

    const int side  = 112 >> l;
    const int start = (l >= 1 ? 12544 : 0) + (l >= 2 ? 3136 : 0) + (l >= 3 ? 784 : 0);
    const float ox = qout[(size_t)bs * 384 + t * 2 + 0];
    const float oy = qout[(size_t)bs * 384 + t * 2 + 1];
    const float xx = rx * side + ox - 0.5f;
    const float yy = ry * side + oy - 0.5f;
    const float xf = floorf(xx), yf = floorf(yy);
    const float lx = xx - xf, ly = yy - yf;
    const int x0 = (int)xf, y0 = (int)yf;
    const float w00 = (1.f - lx) * (1.f - ly) * a, w10 = lx * (1.f - ly) * a;
    const float w01 = (1.f - lx) * ly * a,         w11 = lx * ly * a;
    const bool xv0 = (unsigned)x0 < (unsigned)side, xv1 = (unsigned)(x0 + 1) < (unsigned)side;
    const bool yv0 = (unsigned)y0 < (unsigned)side, yv1 = (unsigned)(y0 + 1) < (unsigned)side;
    const int cx0 = min(max(x0, 0), side - 1), cx1 = min(max(x0 + 1, 0), side - 1);
    const int cy0 = min(max(y0, 0), side - 1), cy1 = min(max(y0 + 1, 0), side - 1);
    const int rowbase = b * kS + start;
    const int t2 = (t & 15) * 8 + (t >> 4);   // sp*8 + h
    sIdx[0][q][t2] = rowbase + cy0 * side + cx0;
    sIdx[1][q][t2] = rowbase + cy0 * side + cx1;
    sIdx[2][q][t2] = rowbase + cy1 * side + cx0;
    sIdx[3][q][t2] = rowbase + cy1 * side + cx1;
    sW[0][q][t2] = (xv0 && yv0) ? w00 : 0.f;
    sW[1][q][t2] = (xv1 && yv0) ? w10 : 0.f;
    sW[2][q][t2] = (xv0 && yv1) ? w01 : 0.f;
    sW[3][q][t2] = (xv1 && yv1) ? w11 : 0.f;
  }
  __syncthreads();

  const int q  = tid >> 6;          // wave = query
  const int h  = (tid >> 3) & 7;
  const int l8 = tid & 7;
  const unsigned short* vb = val + h * 32 + l8 * 4;

  float a0 = 0.f, a1 = 0.f, a2 = 0.f, a3 = 0.f;
#pragma unroll
  for (int sp = 0; sp < 16; ++sp) {
    const int t2 = sp * 8 + h;
#pragma unroll
    for (int c = 0; c < 4; ++c) {
      const int r = sIdx[c][q][t2];
      const float w = sW[c][q][t2];
      const ushort4 v4 = *(const ushort4*)(vb + (size_t)r * 256);
      a0 = fmaf(w, bf2f(v4.x), a0);
      a1 = fmaf(w, bf2f(v4.y), a1);
      a2 = fmaf(w, bf2f(v4.z), a2);
      a3 = fmaf(w, bf2f(v4.w), a3);
    }
  }
  ushort4 o;
  o.x = f2bf(a0); o.y = f2bf(a1); o.z = f2bf(a2); o.w = f2bf(a3);
  *(ushort4*)(outbf + (size_t)(bs0 + q) * 256 + h * 32 + l8 * 4) = o;
}

// ---------------------------------------------------------------------------
__global__ void tail_k(float* __restrict__ out)
{
  if (threadIdx.x == 0) {
    const size_t n = (size_t)kM * kD;
    out[n + 0] = 112.f; out[n + 1] = 112.f;
    out[n + 2] = 56.f;  out[n + 3] = 56.f;
    out[n + 4] = 28.f;  out[n + 5] = 28.f;
    out[n + 6] = 14.f;  out[n + 7] = 14.f;
    out[n + 8] = 0.f;   out[n + 9] = 12544.f;
    out[n + 10] = 15680.f; out[n + 11] = 16464.f;
  }
}

// ---------------------------------------------------------------------------
extern "C" void kernel_launch(void* const* d_in, const int* in_sizes, int n_in,
                              void* d_out, int out_size, void* d_ws, size_t ws_size,
                              hipStream_t stream)
{
  const float* src[4] = {(const float*)d_in[0], (const float*)d_in[2],
                         (const float*)d_in[4], (const float*)d_in[6]};
  const float* pos[4] = {(const float*)d_in[1], (const float*)d_in[3],
                         (const float*)d_in[5], (const float*)d_in[7]};
  const float* lemb  = (const float*)d_in[8];
  const float* off_w = (const float*)d_in[9];
  const float* off_b = (const float*)d_in[10];
  const float* aw_w  = (const float*)d_in[11];
  const float* aw_b  = (const float*)d_in[12];
  const float* val_w = (const float*)d_in[13];
  const float* val_b = (const float*)d_in[14];
  const float* out_w = (const float*)d_in[15];
  const float* out_b = (const float*)d_in[16];
  const float* ln1_s = (const float*)d_in[17];
  const float* ln1_b = (const float*)d_in[18];
  const float* ff1_w = (const float*)d_in[19];
  const float* ff1_b = (const float*)d_in[20];
  const float* ff2_w = (const float*)d_in[21];
  const float* ff2_b = (const float*)d_in[22];
  const float* ln2_s = (const float*)d_in[23];
  const float* ln2_b = (const float*)d_in[24];

  const size_t SZ = (size_t)kMp * kD;      // 8,552,448 floats
  float* ws   = (float*)d_ws;
  float* posb = (float*)d_out;             // pos lives in d_out until last layer
  float* xb   = ws;                        // fp32 [SZ]
  float* R    = ws + SZ;                   // reusable region
  float* qout = R;                         // fp32 [Mp][384] = 1.5*SZ
  unsigned short* valbf = (unsigned short*)(R + SZ + SZ / 2);  // bf16 [Mp][256]
  unsigned short* attbf = (unsigned short*)(R + 2 * SZ);       // bf16 [Mp][256]
  unsigned short* ffbf  = (unsigned short*)R;                  // bf16 [Mp][1024]
  unsigned short* qbf   = (unsigned short*)(ws + 3 * SZ + SZ / 2); // bf16 [Mp][256]
  unsigned short* xbf   = qbf + SZ;                                // bf16 [Mp][256]
  unsigned short* wts   = (unsigned short*)(ws + 4 * SZ + SZ / 2);
  unsigned short* qwT  = wts;                    // [NL][384][256]
  unsigned short* valT = qwT + kNL * 384 * 256;  // [NL][256][256]
  unsigned short* outT = valT + kNL * 256 * 256;
  unsigned short* ff1T = outT + kNL * 256 * 256; // [NL][1024][256]
  unsigned short* ff2T = ff1T + kNL * 1024 * 256;// [NL][256][1024]
  float* qbias = (float*)(ff2T + kNL * 256 * 1024); // [NL][384]

  // --- weight prep ---
  wconv_k<<<dim3(256 / 32, 256 / 32, kNL), 256, 0, stream>>>(off_w, qwT, 256, 256, 0, 384);
  wconv_k<<<dim3(128 / 32, 256 / 32, kNL), 256, 0, stream>>>(aw_w,  qwT, 256, 128, 256, 384);
  wconv_k<<<dim3(256 / 32, 256 / 32, kNL), 256, 0, stream>>>(val_w, valT, 256, 256, 0, 256);
  wconv_k<<<dim3(256 / 32, 256 / 32, kNL), 256, 0, stream>>>(out_w, outT, 256, 256, 0, 256);
  wconv_k<<<dim3(1024 / 32, 256 / 32, kNL), 256, 0, stream>>>(ff1_w, ff1T, 256, 1024, 0, 1024);
  wconv_k<<<dim3(256 / 32, 1024 / 32, kNL), 256, 0, stream>>>(ff2_w, ff2T, 1024, 256, 0, 256);
  biaspack_k<<<(kNL * 384 + 255) / 256, 256, 0, stream>>>(off_b, aw_b, qbias);

  // --- build x0, pos, bf16 copies ---
  const int sides[4]  = {112, 56, 28, 14};
  const int starts[4] = {0, 12544, 15680, 16464};
  for (int l = 0; l < 4; ++l) {
    int HW = sides[l] * sides[l];
    dim3 g((HW + 31) / 32, kD / 32, kB);
    build_xpos_k<<<g, dim3(32, 8), 0, stream>>>(src[l], pos[l], lemb, xb, posb,
                                                xbf, qbf, HW, starts[l], l);
  }

  const dim3 blk(256);
  for (int i = 0; i < kNL; ++i) {
    // qout = (x+pos) @ [off_w | aw_w] + bias   (N=384)
    hgemm64_k<0><<<dim3(3, kMT64), blk, 0, stream>>>(
        qbf, qwT + (size_t)i * 384 * 256, qbias + i * 384, qout, 384, 256);
    // val = x @ val_w + val_b  -> bf16
    hgemm64_k<1><<<dim3(2, kMT64), blk, 0, stream>>>(
        xbf, valT + (size_t)i * 256 * 256, val_b + i * 256, valbf, 256, 256);
    // sampling (+softmax fused)
    msdeform_k<<<kM / 4, blk, 0, stream>>>(valbf, qout, attbf);
    // x = LN1(x + attn @ out_w + out_b)  [fused]
    hgemmln_k<0, 0><<<kMT32, blk, 0, stream>>>(
        attbf, outT + (size_t)i * 256 * 256, out_b + i * 256, xb,
        ln1_s + i * kD, ln1_b + i * kD, nullptr, xb, xbf, nullptr, 256);
    // ffmid = relu(x @ ff1_w + ff1_b) -> bf16
    hgemm_k<1, 1><<<dim3(8, kMT), blk, 0, stream>>>(
        xbf, ff1T + (size_t)i * 1024 * 256, ff1_b + i * 1024, ffbf, 1024, 256);
    // x = LN2(x + ffmid @ ff2_w + ff2_b)  [fused; last layer -> d_out]
    if (i < kNL - 1) {
      hgemmln_k<1, 0><<<kMT32, blk, 0, stream>>>(
          ffbf, ff2T + (size_t)i * 256 * 1024, ff2_b + i * 256, xb,
          ln2_s + i * kD, ln2_b + i * kD, posb, xb, xbf, qbf, 1024);
    } else {
      hgemmln_k<0, 1><<<kMT32, blk, 0, stream>>>(
          ffbf, ff2T + (size_t)i * 256 * 1024, ff2_b + i * 256, xb,
          ln2_s + i * kD, ln2_b + i * kD, nullptr, (float*)d_out, nullptr,
          nullptr, 1024);
    }
  }

  tail_k<<<1, 64, 0, stream>>>((float*)d_out);
}